// Round 26
// baseline (219.762 us; speedup 1.0000x reference)
//
#include <hip/hip_runtime.h>
#include <hip/hip_bf16.h>
#include <math.h>

#define NPB 65536   // pixels per batch (256*256)
#define BATCH 2
#define NTOT (BATCH * NPB)   // 131072

typedef unsigned short u16;
typedef __attribute__((ext_vector_type(8))) short short8;
typedef __attribute__((ext_vector_type(4))) short short4v;
typedef __attribute__((ext_vector_type(4))) float f32x4;

// ---- channel-blocked pixel-major layout for all bf16 intermediates:
//   elem(cb, n, c) at  T[((size_t)cb * NTOT + n) * 16 + c],  c in [0,16)
// ---- weight fragments pre-swizzled as [frag][lane(64)][8] bf16.

__device__ __forceinline__ float bf2f(u16 u) {
  union { unsigned u; float f; } v; v.u = ((unsigned)u) << 16; return v.f;
}
__device__ __forceinline__ u16 f2bf(float f) {
  union { float f; unsigned u; } v; v.f = f;
  unsigned r = v.u + 0x7FFFu + ((v.u >> 16) & 1u);
  return (u16)(r >> 16);
}
__device__ __forceinline__ unsigned pk2(float a, float b) {
  return (unsigned)f2bf(a) | ((unsigned)f2bf(b) << 16);
}
__device__ __forceinline__ f32x4 mm(short8 a, short8 b, f32x4 c) {
  return __builtin_amdgcn_mfma_f32_16x16x32_bf16(a, b, c, 0, 0, 0);
}
__device__ __forceinline__ short8 ldfrag(const u16* F, int frag, int l) {
  return *reinterpret_cast<const short8*>(F + ((size_t)frag * 64 + l) * 8);
}
__device__ __forceinline__ void st4(u16* p, f32x4 c) {
  uint2 v; v.x = pk2(c[0], c[1]); v.y = pk2(c[2], c[3]);
  *reinterpret_cast<uint2*>(p) = v;
}
// tanh-form gelu (max abs err vs exact ~3e-3, validated rounds 9/10/12/13)
__device__ __forceinline__ float gelu_t(float a) {
  const float z = 0.7978845608f * fmaf(0.044715f * a, a * a, a);
  const float e = __expf(2.f * z);
  const float th = 1.f - 2.f / (e + 1.f);
  return 0.5f * a * (1.f + th);
}

// ---------------- W0: pre-swizzle static weights into fragment layout
__global__ __launch_bounds__(64) void k_wprep(
    const float* __restrict__ wqkv, const float* __restrict__ win,
    const float* __restrict__ wout, u16* __restrict__ WQf,
    u16* __restrict__ WIf, u16* __restrict__ WOf)
{
  const int f = blockIdx.x;
  const int l = threadIdx.x;
  const int fr = l & 15, fq = l >> 4;
  short8 v;
  u16* dst;
  if (f < 24) {            // wqkv: frag = t*2+kh, t<12
    const int t = f >> 1, kh = f & 1;
    const int row = t * 16 + fr;
#pragma unroll
    for (int j = 0; j < 8; ++j)
      v[j] = (short)f2bf(wqkv[(size_t)row * 64 + kh * 32 + fq * 8 + j]);
    dst = WQf + ((size_t)f * 64 + l) * 8;
  } else if (f < 68) {     // win: frag = (half*11+t)*2+kh
    const int fi = f - 24;
    const int g = fi >> 1, kh = fi & 1;
    const int half = g / 11, t = g % 11;
    const int col = half * 176 + t * 16 + fr;
    const int row = col < 170 ? col : (col < 176 ? -1 : (col < 346 ? col - 6 : -1));
#pragma unroll
    for (int j = 0; j < 8; ++j)
      v[j] = (row < 0) ? (short)0
             : (short)f2bf(win[(size_t)row * 64 + kh * 32 + fq * 8 + j]);
    dst = WIf + ((size_t)fi * 64 + l) * 8;
  } else {                 // wout: frag = t*6+kh, t<4, kh<6, ld=170
    const int fi = f - 68;
    const int t = fi / 6, kh = fi % 6;
    const int row = t * 16 + fr;
#pragma unroll
    for (int j = 0; j < 8; ++j) {
      const int k = kh * 32 + fq * 8 + j;
      v[j] = (k < 170) ? (short)f2bf(wout[(size_t)row * 170 + k]) : (short)0;
    }
    dst = WOf + ((size_t)fi * 64 + l) * 8;
  }
  *reinterpret_cast<short8*>(dst) = v;
}

// ---------------- G1 fused: LN1 (over 64 ch) + QKVp (12 blocks) = Wqkv * LN(x)
__global__ __launch_bounds__(256, 2) void g_lnqkv(
    const float* __restrict__ x, const float* __restrict__ n1w,
    const float* __restrict__ n1b, const u16* __restrict__ WQf,
    u16* __restrict__ qkvp)
{
  const int l = threadIdx.x & 63, fr = l & 15, fq = l >> 4;
  const int wv = blockIdx.x * 4 + (threadIdx.x >> 6);
  const int nw = gridDim.x * 4;
  short8 A[12][2];
#pragma unroll
  for (int t = 0; t < 12; ++t)
#pragma unroll
    for (int kh = 0; kh < 2; ++kh) A[t][kh] = ldfrag(WQf, t * 2 + kh, l);
  float w0[8], g0[8], w1[8], g1[8];
#pragma unroll
  for (int j = 0; j < 8; ++j) {
    w0[j] = n1w[fq * 8 + j];      g0[j] = n1b[fq * 8 + j];
    w1[j] = n1w[32 + fq * 8 + j]; g1[j] = n1b[32 + fq * 8 + j];
  }
  for (int tile = wv; tile < 8192; tile += nw) {
    const size_t n = (size_t)tile * 16 + fr;
    const int b = (int)(n >> 16);
    const int pix = (int)(n & 65535);
    const float* xb = x + ((size_t)b * 64) * NPB + pix;
    float v0[8], v1[8];
    float s = 0.f;
#pragma unroll
    for (int j = 0; j < 8; ++j) { v0[j] = xb[(size_t)(fq * 8 + j) * NPB]; s += v0[j]; }
#pragma unroll
    for (int j = 0; j < 8; ++j) { v1[j] = xb[(size_t)(32 + fq * 8 + j) * NPB]; s += v1[j]; }
    s += __shfl_xor(s, 16); s += __shfl_xor(s, 32);
    const float mu = s * (1.f / 64.f);
    float ss = 0.f;
#pragma unroll
    for (int j = 0; j < 8; ++j) { float d = v0[j] - mu; ss = fmaf(d, d, ss); }
#pragma unroll
    for (int j = 0; j < 8; ++j) { float d = v1[j] - mu; ss = fmaf(d, d, ss); }
    ss += __shfl_xor(ss, 16); ss += __shfl_xor(ss, 32);
    const float rstd = rsqrtf(ss * (1.f / 64.f) + 1e-5f);
    short8 b0, b1;
#pragma unroll
    for (int j = 0; j < 8; ++j) {
      b0[j] = (short)f2bf((v0[j] - mu) * rstd * w0[j] + g0[j]);
      b1[j] = (short)f2bf((v1[j] - mu) * rstd * w1[j] + g1[j]);
    }
    f32x4 c[12];
#pragma unroll
    for (int t = 0; t < 12; ++t) c[t] = f32x4{0.f, 0.f, 0.f, 0.f};
#pragma unroll
    for (int t = 0; t < 12; ++t) c[t] = mm(A[t][0], b0, c[t]);
#pragma unroll
    for (int t = 0; t < 12; ++t) c[t] = mm(A[t][1], b1, c[t]);
#pragma unroll
    for (int t = 0; t < 12; ++t)
      st4(qkvp + ((size_t)t * NTOT + n) * 16 + fq * 4, c[t]);
  }
}

// ---------------- register-rolling depthwise 3x3 SAME on blocked layout
template<int CH, int STRIP>
__global__ __launch_bounds__(256, 2) void k_dwr(
    const u16* __restrict__ in, u16* __restrict__ out,
    const float* __restrict__ wdw, int wofs)
{
  typedef short __attribute__((ext_vector_type(CH))) shortC;
  constexpr int LPP = 16 / CH;        // lanes per pixel
  constexpr int NX  = 256 / LPP;      // pixels per block in x
  constexpr int XC  = 256 / NX;       // x-chunks per row
  const int t = threadIdx.x;
  const int sub = t % LPP, xi = t / LPP;
  const int q = blockIdx.x / XC, xc = blockIdx.x % XC;
  const int strip = blockIdx.y, b = blockIdx.z;
  const int x = xc * NX + xi;
  const int y0 = strip * STRIP;
  const int e0 = sub * CH;
  const int c0 = q * 16 + e0;

  const u16* pin = in + ((size_t)q * NTOT + (size_t)b * NPB) * 16 + e0;

  float w[9][CH];
#pragma unroll
  for (int ch = 0; ch < CH; ++ch) {
    const int row = wofs + c0 + ch;
#pragma unroll
    for (int tap = 0; tap < 9; ++tap)
      w[tap][ch] = wdw[(size_t)row * 9 + tap];
  }

  auto LD = [&](int yy, int xx) -> shortC {
    shortC v;
#pragma unroll
    for (int j = 0; j < CH; ++j) v[j] = 0;
    if ((unsigned)yy < 256u && (unsigned)xx < 256u)
      v = *reinterpret_cast<const shortC*>(pin + (size_t)(yy * 256 + xx) * 16);
    return v;
  };

  shortC r[3][3];
  r[0][0] = LD(y0 - 1, x - 1); r[0][1] = LD(y0 - 1, x); r[0][2] = LD(y0 - 1, x + 1);
  r[1][0] = LD(y0, x - 1);     r[1][1] = LD(y0, x);     r[1][2] = LD(y0, x + 1);

#pragma unroll 2
  for (int yy = 0; yy < STRIP; ++yy) {
    const int y = y0 + yy;
    r[2][0] = LD(y + 1, x - 1); r[2][1] = LD(y + 1, x); r[2][2] = LD(y + 1, x + 1);
    float acc[CH];
#pragma unroll
    for (int ch = 0; ch < CH; ++ch) acc[ch] = 0.f;
#pragma unroll
    for (int ky = 0; ky < 3; ++ky)
#pragma unroll
      for (int kx = 0; kx < 3; ++kx)
#pragma unroll
        for (int ch = 0; ch < CH; ++ch)
          acc[ch] = fmaf(w[ky * 3 + kx][ch], bf2f((u16)r[ky][kx][ch]), acc[ch]);
    u16* po = out + ((size_t)q * NTOT + (size_t)b * NPB +
                     (size_t)(y * 256 + x)) * 16 + e0;
    uint4 o;
    o.x = pk2(acc[0], acc[1]); o.y = pk2(acc[2], acc[3]);
    o.z = pk2(acc[4], acc[5]); o.w = pk2(acc[6], acc[7]);
    *reinterpret_cast<uint4*>(po) = o;
#pragma unroll
    for (int dx = 0; dx < 3; ++dx) { r[0][dx] = r[1][dx]; r[1][dx] = r[2][dx]; }
  }
}

// ---------------- FUSED: vf = dw3x3(P_b * v); X2 = x + M2_b*vf; Y2 = LN2(X2)
__global__ __launch_bounds__(256, 2) void g_pvdwln(
    const u16* __restrict__ QKV, const u16* __restrict__ Pf,
    const float* __restrict__ wkvd, const u16* __restrict__ M2f,
    const float* __restrict__ x, const float* __restrict__ n2w,
    const float* __restrict__ n2b, u16* __restrict__ X2,
    u16* __restrict__ Y2)
{
  __shared__ __align__(16) u16 sh[336 * 68];        // vfp halo: 64 ch + 4 pad
  __shared__ __align__(16) u16 lds_vf[4 * 256 * 16]; // vf tile, blocked [cb][lpix][16]
  __shared__ __align__(16) u16 swt[9 * 64];          // dw weights bf16 [tap][c]
  const int t = threadIdx.x;
  const int tx0 = blockIdx.x * 16, ty0 = blockIdx.y * 16;
  const int b = blockIdx.z;
  const size_t bofs = (size_t)b * NPB;

  for (int i = t; i < 9 * 64; i += 256) {
    const int tap = i >> 6, c = i & 63;
    swt[i] = f2bf(wkvd[((size_t)(64 + c)) * 9 + tap]);
  }

  const int w = t >> 6, l = t & 63, fr = l & 15, fq = l >> 4;
  short8 A[4][2];
#pragma unroll
  for (int tt = 0; tt < 4; ++tt)
#pragma unroll
    for (int kh = 0; kh < 2; ++kh)
      A[tt][kh] = ldfrag(Pf, (b * 4 + tt) * 2 + kh, l);
  const size_t hof = (size_t)(fq & 1) * 8;

  // --- Phase A: vfp for 21 halo pixel-tiles (rows 0..335, valid 0..323)
  for (int i = w; i < 21; i += 4) {
    const int hidx = i * 16 + fr;
    const int hs = hidx < 323 ? hidx : 323;
    const int py = hs / 18, px = hs % 18;
    const int gy = ty0 + py - 1, gx = tx0 + px - 1;
    const bool ok = ((unsigned)gy < 256u) && ((unsigned)gx < 256u);
    short8 b0, b1;
    if (ok) {
      const size_t pix = bofs + (size_t)(gy * 256 + gx);
      b0 = *reinterpret_cast<const short8*>(
          QKV + ((size_t)(8 + (fq >> 1)) * NTOT + pix) * 16 + hof);
      b1 = *reinterpret_cast<const short8*>(
          QKV + ((size_t)(10 + (fq >> 1)) * NTOT + pix) * 16 + hof);
    } else {
#pragma unroll
      for (int j = 0; j < 8; ++j) { b0[j] = 0; b1[j] = 0; }
    }
    f32x4 c[4];
#pragma unroll
    for (int tt = 0; tt < 4; ++tt) c[tt] = f32x4{0.f, 0.f, 0.f, 0.f};
#pragma unroll
    for (int tt = 0; tt < 4; ++tt) c[tt] = mm(A[tt][0], b0, c[tt]);
#pragma unroll
    for (int tt = 0; tt < 4; ++tt) c[tt] = mm(A[tt][1], b1, c[tt]);
    u16* dp = &sh[hidx * 68];
#pragma unroll
    for (int tt = 0; tt < 4; ++tt) st4(dp + tt * 16 + fq * 4, c[tt]);
  }
  __syncthreads();

  // --- Phase B: dwconv; thread = (4 ch, 1 col, 4 rows); write vf tile to LDS
  {
    const int sub = t & 3, colx = (t >> 2) & 15, rg = t >> 6;
    const int e0 = sub * 4;
    for (int cb = 0; cb < 4; ++cb) {
      float wf[9][4];
#pragma unroll
      for (int tap = 0; tap < 9; ++tap)
#pragma unroll
        for (int j = 0; j < 4; ++j)
          wf[tap][j] = bf2f(swt[tap * 64 + cb * 16 + e0 + j]);
      short4v rwin[3][3];
      auto LDR = [&](int hr, int slot) {
#pragma unroll
        for (int dx = 0; dx < 3; ++dx)
          rwin[slot][dx] = *reinterpret_cast<const short4v*>(
              &sh[(hr * 18 + colx + dx) * 68 + cb * 16 + e0]);
      };
      const int r0 = rg * 4;
      LDR(r0, 0); LDR(r0 + 1, 1);
#pragma unroll
      for (int k = 0; k < 4; ++k) {
        LDR(r0 + k + 2, (k + 2) % 3);
        const int s0 = k % 3, s1 = (k + 1) % 3, s2 = (k + 2) % 3;
        float acc[4] = {0.f, 0.f, 0.f, 0.f};
#pragma unroll
        for (int dx = 0; dx < 3; ++dx)
#pragma unroll
          for (int j = 0; j < 4; ++j) {
            acc[j] = fmaf(wf[0 + dx][j], bf2f((u16)rwin[s0][dx][j]), acc[j]);
            acc[j] = fmaf(wf[3 + dx][j], bf2f((u16)rwin[s1][dx][j]), acc[j]);
            acc[j] = fmaf(wf[6 + dx][j], bf2f((u16)rwin[s2][dx][j]), acc[j]);
          }
        const int lpix = (r0 + k) * 16 + colx;
        uint2 o; o.x = pk2(acc[0], acc[1]); o.y = pk2(acc[2], acc[3]);
        *reinterpret_cast<uint2*>(&lds_vf[(cb * 256 + lpix) * 16 + e0]) = o;
      }
    }
  }
  __syncthreads();

  // --- Phase C: X2 = x + M2_b*vf; Y2 = LN2(X2)  (g_x2ln body, 4 rows/wave)
  {
    short8 Am[4][2];
#pragma unroll
    for (int tt = 0; tt < 4; ++tt)
#pragma unroll
      for (int kh = 0; kh < 2; ++kh)
        Am[tt][kh] = ldfrag(M2f, (b * 4 + tt) * 2 + kh, l);
#pragma unroll
    for (int kk = 0; kk < 4; ++kk) {
      const int row = w * 4 + kk;          // tile row 0..15
      const int lpix = row * 16 + fr;      // pixel within tile
      const int pix = (ty0 + row) * 256 + tx0 + fr;
      const size_t n = bofs + (size_t)pix;
      const short8 b0 = *reinterpret_cast<const short8*>(
          &lds_vf[((size_t)(fq >> 1) * 256 + lpix) * 16 + hof]);
      const short8 b1 = *reinterpret_cast<const short8*>(
          &lds_vf[((size_t)(2 + (fq >> 1)) * 256 + lpix) * 16 + hof]);
      f32x4 c[4];
#pragma unroll
      for (int tt = 0; tt < 4; ++tt) c[tt] = f32x4{0.f, 0.f, 0.f, 0.f};
#pragma unroll
      for (int tt = 0; tt < 4; ++tt) c[tt] = mm(Am[tt][0], b0, c[tt]);
#pragma unroll
      for (int tt = 0; tt < 4; ++tt) c[tt] = mm(Am[tt][1], b1, c[tt]);
#pragma unroll
      for (int tt = 0; tt < 4; ++tt)
#pragma unroll
        for (int r = 0; r < 4; ++r)
          c[tt][r] += x[((size_t)(b * 64 + tt * 16 + fq * 4 + r)) * NPB + pix];
#pragma unroll
      for (int tt = 0; tt < 4; ++tt)
        st4(X2 + ((size_t)tt * NTOT + n) * 16 + fq * 4, c[tt]);
      float s = 0.f;
#pragma unroll
      for (int tt = 0; tt < 4; ++tt)
#pragma unroll
        for (int r = 0; r < 4; ++r) s += c[tt][r];
      s += __shfl_xor(s, 16); s += __shfl_xor(s, 32);
      const float mu = s * (1.f / 64.f);
      float ss = 0.f;
#pragma unroll
      for (int tt = 0; tt < 4; ++tt)
#pragma unroll
        for (int r = 0; r < 4; ++r) { float d = c[tt][r] - mu; ss = fmaf(d, d, ss); }
      ss += __shfl_xor(ss, 16); ss += __shfl_xor(ss, 32);
      const float rstd = rsqrtf(ss * (1.f / 64.f) + 1e-5f);
#pragma unroll
      for (int tt = 0; tt < 4; ++tt)
#pragma unroll
        for (int r = 0; r < 4; ++r) {
          const int oc = tt * 16 + fq * 4 + r;
          c[tt][r] = (c[tt][r] - mu) * rstd * n2w[oc] + n2b[oc];
        }
#pragma unroll
      for (int tt = 0; tt < 4; ++tt)
        st4(Y2 + ((size_t)tt * NTOT + n) * 16 + fq * 4, c[tt]);
    }
  }
}

// ---------------- FUSED: Hg = gelu(dw3x3(Win*Y2)_x1) * dw3x3(Win*Y2)_x2
// 8x16 output tile (halo 10x18=180, padded 192): LDS 47.8 KB -> 3 blocks/CU
// (was 16x16 / 79.4 KB / 2 blocks; kernel is latency-bound at 17% occupancy).
__global__ __launch_bounds__(256, 2) void g_windwg(
    const u16* __restrict__ Y2, const u16* __restrict__ WIf,
    const float* __restrict__ wdw, u16* __restrict__ Hg)
{
  __shared__ __align__(16) u16 sy[192 * 72];    // halo Y2, row stride 72
  __shared__ __align__(16) u16 sh[192 * 36];    // hpre x1(0..15) x2(16..31)
  __shared__ __align__(16) u16 swt[2 * 9 * 176]; // transposed dw weights bf16
  const int t = threadIdx.x;
  const int tx0 = blockIdx.x * 16, ty0 = blockIdx.y * 8;
  const int b = blockIdx.z;
  const size_t bofs = (size_t)b * NPB;

  for (int i = t; i < 2 * 9 * 176; i += 256) {
    const int pl = i / (9 * 176);
    const int r = i % (9 * 176);
    const int tap = r / 176, c = r % 176;
    swt[i] = (c < 170) ? f2bf(wdw[((size_t)(pl * 170 + c)) * 9 + tap]) : (u16)0;
  }
  if (t < 192) {
    const int py = t / 18, px = t % 18;
    const int gy = ty0 + py - 1, gx = tx0 + px - 1;
    const bool ok = (t < 180) && ((unsigned)gy < 256u) && ((unsigned)gx < 256u);
#pragma unroll
    for (int cb = 0; cb < 4; ++cb) {
      short8 v0, v1;
      if (ok) {
        const u16* src = Y2 + ((size_t)cb * NTOT + bofs + (size_t)(gy * 256 + gx)) * 16;
        v0 = *reinterpret_cast<const short8*>(src);
        v1 = *reinterpret_cast<const short8*>(src + 8);
      } else {
#pragma unroll
        for (int j = 0; j < 8; ++j) { v0[j] = 0; v1[j] = 0; }
      }
      *reinterpret_cast<short8*>(&sy[t * 72 + cb * 16]) = v0;
      *reinterpret_cast<short8*>(&sy[t * 72 + cb * 16 + 8]) = v1;
    }
  }
  __syncthreads();

  const int w = t >> 6, l = t & 63, fr = l & 15, fq = l >> 4;
  const int sub = t & 3, colx = (t >> 2) & 15, rg = t >> 6;
  const int e0 = sub * 4;

  for (int q = 0; q < 11; ++q) {
    const short8 a10 = ldfrag(WIf, q * 2, l);
    const short8 a11 = ldfrag(WIf, q * 2 + 1, l);
    const short8 a20 = ldfrag(WIf, (11 + q) * 2, l);
    const short8 a21 = ldfrag(WIf, (11 + q) * 2 + 1, l);
    for (int i = w; i < 12; i += 4) {
      const u16* sp = &sy[(i * 16 + fr) * 72];
      const short8 b0 = *reinterpret_cast<const short8*>(sp + fq * 8);
      const short8 b1 = *reinterpret_cast<const short8*>(sp + 32 + fq * 8);
      f32x4 c1 = {0.f, 0.f, 0.f, 0.f}, c2 = {0.f, 0.f, 0.f, 0.f};
      c1 = mm(a10, b0, c1); c1 = mm(a11, b1, c1);
      c2 = mm(a20, b0, c2); c2 = mm(a21, b1, c2);
      u16* dp = &sh[(i * 16 + fr) * 36];
      st4(dp + fq * 4, c1);
      st4(dp + 16 + fq * 4, c2);
    }
    __syncthreads();

    float wf[2][9][4];
#pragma unroll
    for (int pl = 0; pl < 2; ++pl)
#pragma unroll
      for (int tap = 0; tap < 9; ++tap) {
        const short4v wv = *reinterpret_cast<const short4v*>(
            &swt[(pl * 9 + tap) * 176 + q * 16 + e0]);
#pragma unroll
        for (int j = 0; j < 4; ++j) wf[pl][tap][j] = bf2f((u16)wv[j]);
      }
    short4v rwin[3][3][2];
    auto LDR = [&](int hr, int slot) {
#pragma unroll
      for (int dx = 0; dx < 3; ++dx)
#pragma unroll
        for (int pl = 0; pl < 2; ++pl)
          rwin[slot][dx][pl] = *reinterpret_cast<const short4v*>(
              &sh[(hr * 18 + colx + dx) * 36 + pl * 16 + e0]);
    };
    const int r0 = rg * 2;
    LDR(r0, 0); LDR(r0 + 1, 1);
#pragma unroll
    for (int k = 0; k < 2; ++k) {
      LDR(r0 + k + 2, (k + 2) % 3);
      const int s0 = k % 3, s1 = (k + 1) % 3, s2 = (k + 2) % 3;
      float acc[2][4] = {{0.f, 0.f, 0.f, 0.f}, {0.f, 0.f, 0.f, 0.f}};
#pragma unroll
      for (int pl = 0; pl < 2; ++pl)
#pragma unroll
        for (int dx = 0; dx < 3; ++dx)
#pragma unroll
          for (int j = 0; j < 4; ++j) {
            acc[pl][j] = fmaf(wf[pl][0 + dx][j], bf2f((u16)rwin[s0][dx][pl][j]), acc[pl][j]);
            acc[pl][j] = fmaf(wf[pl][3 + dx][j], bf2f((u16)rwin[s1][dx][pl][j]), acc[pl][j]);
            acc[pl][j] = fmaf(wf[pl][6 + dx][j], bf2f((u16)rwin[s2][dx][pl][j]), acc[pl][j]);
          }
      float v[4];
#pragma unroll
      for (int j = 0; j < 4; ++j) v[j] = gelu_t(acc[0][j]) * acc[1][j];
      const int gy = ty0 + r0 + k, gx = tx0 + colx;
      uint2 o; o.x = pk2(v[0], v[1]); o.y = pk2(v[2], v[3]);
      *reinterpret_cast<uint2*>(
          Hg + ((size_t)q * NTOT + bofs + (size_t)(gy * 256 + gx)) * 16 + e0) = o;
    }
    __syncthreads();
  }
}

// ---------------- gram/norm partials via MFMA (blocked: q=block h, k=block 4+h)
__global__ __launch_bounds__(256, 2) void k_gram_p(
    const u16* __restrict__ qkv, float* __restrict__ part)
{
  __shared__ __align__(16) u16 lds[32][520];
  const int chunk = blockIdx.x, h = blockIdx.y, b = blockIdx.z;
  const int t = threadIdx.x;
#pragma unroll
  for (int i = 0; i < 2; ++i) {
    const int p = t + i * 256;
    const size_t pix = (size_t)b * NPB + chunk * 512 + p;
    const u16* srcq = qkv + ((size_t)h * NTOT + pix) * 16;
    const u16* srck = qkv + ((size_t)(4 + h) * NTOT + pix) * 16;
    const short8 q0 = *reinterpret_cast<const short8*>(srcq);
    const short8 q1 = *reinterpret_cast<const short8*>(srcq + 8);
    const short8 k0 = *reinterpret_cast<const short8*>(srck);
    const short8 k1 = *reinterpret_cast<const short8*>(srck + 8);
#pragma unroll
    for (int j = 0; j < 8; ++j) {
      lds[j][p] = (u16)q0[j];  lds[8 + j][p] = (u16)q1[j];
      lds[16 + j][p] = (u16)k0[j]; lds[24 + j][p] = (u16)k1[j];
    }
  }
  __syncthreads();
  const int w = t >> 6, l = t & 63, fr = l & 15, fq = l >> 4;
  if (w >= 3) return;
  float* pp = part + ((size_t)((b * 4 + h) * 128) + chunk) * 288;
  const int rowA = (w == 2) ? 16 + fr : fr;
  const int rowB = (w == 0) ? 16 + fr : rowA;
  f32x4 acc = {0.f, 0.f, 0.f, 0.f};
#pragma unroll
  for (int kt = 0; kt < 16; ++kt) {
    const short8 a  = *reinterpret_cast<const short8*>(&lds[rowA][kt * 32 + fq * 8]);
    const short8 bb = *reinterpret_cast<const short8*>(&lds[rowB][kt * 32 + fq * 8]);
    acc = mm(a, bb, acc);
  }
  if (w == 0) {
#pragma unroll
    for (int r = 0; r < 4; ++r) pp[(fq * 4 + r) * 16 + fr] = acc[r];
  } else if ((fr >> 2) == fq) {
    pp[(w == 1 ? 256 : 272) + fr] = acc[fr & 3];
  }
}

// ---------------- reduce partials over 128 chunks
__global__ __launch_bounds__(320) void k_gram_red(
    const float* __restrict__ part, float* __restrict__ G,
    float* __restrict__ Sq, float* __restrict__ Sk)
{
  const int bh = blockIdx.x;
  const int t = threadIdx.x;
  if (t >= 288) return;
  const float* p = part + (size_t)bh * 128 * 288 + t;
  float s = 0.f;
  for (int ch = 0; ch < 128; ++ch) s += p[(size_t)ch * 288];
  const int b = bh >> 2, h = bh & 3;
  if (t < 256) G[bh * 256 + t] = s;
  else if (t < 272) Sq[b * 64 + h * 16 + (t - 256)] = s;
  else Sk[b * 64 + h * 16 + (t - 272)] = s;
}

// ---------------- softmax + fold conv matrices; emit Pf/M2f fragment layout
__global__ __launch_bounds__(256) void k_attn(
    const float* __restrict__ G, const float* __restrict__ Sq,
    const float* __restrict__ Sk, const float* __restrict__ temp,
    const float* __restrict__ wpo, const float* __restrict__ wkv,
    const float* __restrict__ wpof, u16* __restrict__ Pf,
    u16* __restrict__ M2f)
{
  __shared__ float attn[BATCH][4][16][16];
  __shared__ float M1[BATCH][64][64];
  __shared__ float rq[128], rk[128];
  const int t = threadIdx.x;
  if (t < 128) {
    rq[t] = 1.f / fmaxf(sqrtf(Sq[t]), 1e-12f);
    rk[t] = 1.f / fmaxf(sqrtf(Sk[t]), 1e-12f);
  }
  __syncthreads();
  if (t < 128) {
    const int b = t >> 6, h = (t >> 4) & 3, d = t & 15;
    const float tm = temp[h];
    const float* g = G + ((b * 4 + h) * 16 + d) * 16;
    const float rqd = rq[b * 64 + h * 16 + d];
    float L[16], mx = -1e30f;
#pragma unroll
    for (int e = 0; e < 16; ++e) {
      L[e] = g[e] * rqd * rk[b * 64 + h * 16 + e] * tm;
      mx = fmaxf(mx, L[e]);
    }
    float s = 0.f;
#pragma unroll
    for (int e = 0; e < 16; ++e) { L[e] = expf(L[e] - mx); s += L[e]; }
    const float inv = 1.f / s;
#pragma unroll
    for (int e = 0; e < 16; ++e) attn[b][h][d][e] = L[e] * inv;
  }
  __syncthreads();
  for (int s0 = 0; s0 < 32; ++s0) {
    const int idx = t * 32 + s0;
    const int b = idx >> 12, o = (idx >> 6) & 63, c = idx & 63;
    const int h = c >> 4, e = c & 15;
    float a = 0.f;
#pragma unroll
    for (int d = 0; d < 16; ++d) a = fmaf(wpo[o * 64 + h * 16 + d], attn[b][h][d][e], a);
    M1[b][o][c] = a;
  }
  __syncthreads();
  for (int it = 0; it < 4; ++it) {
    const int idx = it * 256 + t;
    const int l = idx & 63;
    const int fi = idx >> 6;
    const int b = fi >> 3, tt = (fi >> 1) & 3, kh = fi & 1;
    const int fr = l & 15, fq = l >> 4;
    const int o = tt * 16 + fr;
    short8 pv, mv;
#pragma unroll
    for (int j = 0; j < 8; ++j) {
      const int c = kh * 32 + fq * 8 + j;
      const int h = c >> 4, e = c & 15;
      float a2 = 0.f;
#pragma unroll
      for (int d = 0; d < 16; ++d)
        a2 = fmaf(wpof[o * 64 + h * 16 + d], attn[b][h][d][e], a2);
      mv[j] = (short)f2bf(a2);
      float a = 0.f;
      for (int jj = 0; jj < 64; ++jj)
        a = fmaf(wkv[(64 + o) * 64 + jj], M1[b][jj][c], a);
      pv[j] = (short)f2bf(a);
    }
    *reinterpret_cast<short8*>(Pf + ((size_t)fi * 64 + l) * 8) = pv;
    *reinterpret_cast<short8*>(M2f + ((size_t)fi * 64 + l) * 8) = mv;
  }
}

// ---------------- G5: out = X2 + Wout(64x170) * Hg (11 blocks)
__global__ __launch_bounds__(256, 2) void g_out(
    const u16* __restrict__ hg, const u16* __restrict__ WOf,
    const u16* __restrict__ X2, float* __restrict__ out)
{
  const int l = threadIdx.x & 63, fr = l & 15, fq = l >> 4;
  const int wv = blockIdx.x * 4 + (threadIdx.x >> 6);
  const int nw = gridDim.x * 4;
  short8 A[4][6];
#pragma unroll
  for (int t = 0; t < 4; ++t)
#pragma unroll
    for (int kh = 0; kh < 6; ++kh)
      A[t][kh] = ldfrag(WOf, t * 6 + kh, l);
  const size_t hof = (size_t)(fq & 1) * 8;
  for (int tile = wv; tile < 8192; tile += nw) {
    const size_t n = (size_t)tile * 16 + fr;
    short8 bb[6];
#pragma unroll
    for (int kh = 0; kh < 6; ++kh) {
      int hb = kh * 2 + (fq >> 1);
      if (hb > 10) hb = 10;  // k>=170 weights are zero; value irrelevant
      bb[kh] = *reinterpret_cast<const short8*>(
          hg + ((size_t)hb * NTOT + n) * 16 + hof);
    }
    f32x4 c[4];
#pragma unroll
    for (int t = 0; t < 4; ++t) c[t] = f32x4{0.f, 0.f, 0.f, 0.f};
#pragma unroll
    for (int kh = 0; kh < 6; ++kh)
#pragma unroll
      for (int t = 0; t < 4; ++t) c[t] = mm(A[t][kh], bb[kh], c[t]);
    const int b = (int)(n >> 16);
    const int pix = (int)(n & 65535);
#pragma unroll
    for (int t = 0; t < 4; ++t) {
      const uint2 xv = *reinterpret_cast<const uint2*>(
          X2 + ((size_t)t * NTOT + n) * 16 + fq * 4);
      const u16 h0 = (u16)(xv.x & 0xffff), h1 = (u16)(xv.x >> 16);
      const u16 h2 = (u16)(xv.y & 0xffff), h3 = (u16)(xv.y >> 16);
      const int ocb = b * 64 + t * 16 + fq * 4;
      out[((size_t)(ocb + 0)) * NPB + pix] = c[t][0] + bf2f(h0);
      out[((size_t)(ocb + 1)) * NPB + pix] = c[t][1] + bf2f(h1);
      out[((size_t)(ocb + 2)) * NPB + pix] = c[t][2] + bf2f(h2);
      out[((size_t)(ocb + 3)) * NPB + pix] = c[t][3] + bf2f(h3);
    }
  }
}

extern "C" void kernel_launch(void* const* d_in, const int* in_sizes, int n_in,
                              void* d_out, int out_size, void* d_ws, size_t ws_size,
                              hipStream_t stream)
{
  const float* x     = (const float*)d_in[0];
  const float* n1w   = (const float*)d_in[1];
  const float* n1b   = (const float*)d_in[2];
  const float* temp  = (const float*)d_in[3];
  const float* wqkv  = (const float*)d_in[4];
  const float* wqkvd = (const float*)d_in[5];
  const float* wpo   = (const float*)d_in[6];
  const float* wkv   = (const float*)d_in[7];
  const float* wkvd  = (const float*)d_in[8];
  const float* wpof  = (const float*)d_in[9];
  const float* n2w   = (const float*)d_in[10];
  const float* n2b   = (const float*)d_in[11];
  const float* win   = (const float*)d_in[12];
  const float* wdw   = (const float*)d_in[13];
  const float* wout  = (const float*)d_in[14];
  float* out = (float*)d_out;

  char* ws = (char*)d_ws;
  const size_t offA  = 0;                       // 16.78 MB: Y2
  const size_t offB  = 16777216;                // 50.33 MB: QKVp (VF eliminated)
  const size_t offC  = offB + 50331648;         // 50.33 MB: QKV
  const size_t offHg = offC + 50331648;         // 46.14 MB (11 blocks)
  const size_t offX2 = offHg + 46137344 + 256;  // 16.78 MB
  const size_t offSm = offX2 + 16777216;

  u16* Y2   = (u16*)(ws + offA);
  u16* QKVp = (u16*)(ws + offB);
  u16* QKV  = (u16*)(ws + offC);
  u16* Hg   = (u16*)(ws + offHg);
  u16* X2   = (u16*)(ws + offX2);
  float* part = (float*)(ws + offSm);                     // 1,179,648 B
  float* G    = (float*)(ws + offSm + 1179648);           // 8 KB
  float* Sq   = (float*)(ws + offSm + 1179648 + 8192);    // 512 B
  float* Sk   = (float*)(ws + offSm + 1179648 + 8704);    // 512 B
  u16* Pf     = (u16*)(ws + offSm + 1179648 + 9216);      // 16 KB
  u16* M2f    = (u16*)(ws + offSm + 1179648 + 25600);     // 16 KB
  u16* WQf    = (u16*)(ws + offSm + 1179648 + 41984);     // 24 KB
  u16* WIf    = (u16*)(ws + offSm + 1179648 + 66560);     // 44 KB
  u16* WOf    = (u16*)(ws + offSm + 1179648 + 111616);    // 24 KB

  k_wprep<<<dim3(92), 64, 0, stream>>>(wqkv, win, wout, WQf, WIf, WOf);
  // fused LN1 + QKV GEMM (Y1 tensor eliminated)
  g_lnqkv<<<dim3(512), 256, 0, stream>>>(x, n1w, n1b, WQf, QKVp);
  // dw 192ch: 12 blocks x 2 xchunks, 16 strips, 2 batches
  k_dwr<8, 16><<<dim3(24, 16, BATCH), 256, 0, stream>>>(QKVp, QKV, wqkvd, 0);
  k_gram_p<<<dim3(128, 4, BATCH), 256, 0, stream>>>(QKV, part);
  k_gram_red<<<dim3(BATCH * 4), 320, 0, stream>>>(part, G, Sq, Sk);
  k_attn<<<dim3(1), 256, 0, stream>>>(G, Sq, Sk, temp, wpo, wkv, wpof, Pf, M2f);
  // fused PV GEMM + dw 64ch + M2 GEMM + residual + LN2 (VF tensor eliminated)
  g_pvdwln<<<dim3(16, 16, BATCH), 256, 0, stream>>>(
      QKV, Pf, wkvd, M2f, x, n2w, n2b, X2, Y2);
  // fused Win GEMM + gated dwconv: 8x16 tiles, 3 blocks/CU
  g_windwg<<<dim3(16, 32, BATCH), 256, 0, stream>>>(Y2, WIf, wdw, Hg);
  g_out<<<dim3(512), 256, 0, stream>>>(Hg, WOf, X2, out);
}

// Round 27
// 206.690 us; speedup vs baseline: 1.0632x; 1.0632x over previous
//
#include <hip/hip_runtime.h>
#include <hip/hip_bf16.h>
#include <math.h>

#define NPB 65536   // pixels per batch (256*256)
#define BATCH 2
#define NTOT (BATCH * NPB)   // 131072

typedef unsigned short u16;
typedef __attribute__((ext_vector_type(8))) short short8;
typedef __attribute__((ext_vector_type(4))) short short4v;
typedef __attribute__((ext_vector_type(4))) float f32x4;

// ---- channel-blocked pixel-major layout for all bf16 intermediates:
//   elem(cb, n, c) at  T[((size_t)cb * NTOT + n) * 16 + c],  c in [0,16)
// ---- weight fragments pre-swizzled as [frag][lane(64)][8] bf16.

__device__ __forceinline__ float bf2f(u16 u) {
  union { unsigned u; float f; } v; v.u = ((unsigned)u) << 16; return v.f;
}
__device__ __forceinline__ u16 f2bf(float f) {
  union { float f; unsigned u; } v; v.f = f;
  unsigned r = v.u + 0x7FFFu + ((v.u >> 16) & 1u);
  return (u16)(r >> 16);
}
__device__ __forceinline__ unsigned pk2(float a, float b) {
  return (unsigned)f2bf(a) | ((unsigned)f2bf(b) << 16);
}
__device__ __forceinline__ f32x4 mm(short8 a, short8 b, f32x4 c) {
  return __builtin_amdgcn_mfma_f32_16x16x32_bf16(a, b, c, 0, 0, 0);
}
__device__ __forceinline__ short8 ldfrag(const u16* F, int frag, int l) {
  return *reinterpret_cast<const short8*>(F + ((size_t)frag * 64 + l) * 8);
}
__device__ __forceinline__ void st4(u16* p, f32x4 c) {
  uint2 v; v.x = pk2(c[0], c[1]); v.y = pk2(c[2], c[3]);
  *reinterpret_cast<uint2*>(p) = v;
}
// tanh-form gelu (max abs err vs exact ~3e-3, validated rounds 9/10/12/13)
__device__ __forceinline__ float gelu_t(float a) {
  const float z = 0.7978845608f * fmaf(0.044715f * a, a * a, a);
  const float e = __expf(2.f * z);
  const float th = 1.f - 2.f / (e + 1.f);
  return 0.5f * a * (1.f + th);
}

// ---------------- W0: pre-swizzle static weights into fragment layout
// f<24: WQf; f<68: WIf; f<92: WOf; f<202: WDf = diagonal-A dwconv frags
// for g_windwg (pl in {x1,x2}, tap-pair p in [0,5), q in [0,11)):
//   A[ch=fr][k=fq*8+j] = wdw[pl][tap=2p+(fq>>1)][q*16+fr] iff (k&15)==fr.
__global__ __launch_bounds__(64) void k_wprep(
    const float* __restrict__ wqkv, const float* __restrict__ win,
    const float* __restrict__ wout, const float* __restrict__ wdw,
    u16* __restrict__ WQf, u16* __restrict__ WIf, u16* __restrict__ WOf,
    u16* __restrict__ WDf)
{
  const int f = blockIdx.x;
  const int l = threadIdx.x;
  const int fr = l & 15, fq = l >> 4;
  short8 v;
  u16* dst;
  if (f < 24) {            // wqkv: frag = t*2+kh, t<12
    const int t = f >> 1, kh = f & 1;
    const int row = t * 16 + fr;
#pragma unroll
    for (int j = 0; j < 8; ++j)
      v[j] = (short)f2bf(wqkv[(size_t)row * 64 + kh * 32 + fq * 8 + j]);
    dst = WQf + ((size_t)f * 64 + l) * 8;
  } else if (f < 68) {     // win: frag = (half*11+t)*2+kh
    const int fi = f - 24;
    const int g = fi >> 1, kh = fi & 1;
    const int half = g / 11, t = g % 11;
    const int col = half * 176 + t * 16 + fr;
    const int row = col < 170 ? col : (col < 176 ? -1 : (col < 346 ? col - 6 : -1));
#pragma unroll
    for (int j = 0; j < 8; ++j)
      v[j] = (row < 0) ? (short)0
             : (short)f2bf(win[(size_t)row * 64 + kh * 32 + fq * 8 + j]);
    dst = WIf + ((size_t)fi * 64 + l) * 8;
  } else if (f < 92) {     // wout: frag = t*6+kh, t<4, kh<6, ld=170
    const int fi = f - 68;
    const int t = fi / 6, kh = fi % 6;
    const int row = t * 16 + fr;
#pragma unroll
    for (int j = 0; j < 8; ++j) {
      const int k = kh * 32 + fq * 8 + j;
      v[j] = (k < 170) ? (short)f2bf(wout[(size_t)row * 170 + k]) : (short)0;
    }
    dst = WOf + ((size_t)fi * 64 + l) * 8;
  } else {                 // WDf: fd = pl*55 + p*11 + q
    const int fd = f - 92;
    const int pl = fd / 55, rest = fd % 55;
    const int p = rest / 11, q = rest % 11;
    const int tap = 2 * p + (fq >> 1);
    const int c = q * 16 + fr;
    const int ts = tap < 9 ? tap : 0;
    const int cs = c < 170 ? c : 0;
    const float wv = wdw[((size_t)(pl * 170 + cs)) * 9 + ts];
    const bool act = (tap < 9) && (c < 170) && ((fq & 1) == (fr >> 3));
#pragma unroll
    for (int j = 0; j < 8; ++j)
      v[j] = (act && j == (fr & 7)) ? (short)f2bf(wv) : (short)0;
    dst = WDf + ((size_t)fd * 64 + l) * 8;
  }
  *reinterpret_cast<short8*>(dst) = v;
}

// ---------------- G1 fused: LN1 (over 64 ch) + QKVp (12 blocks) = Wqkv * LN(x)
__global__ __launch_bounds__(256, 2) void g_lnqkv(
    const float* __restrict__ x, const float* __restrict__ n1w,
    const float* __restrict__ n1b, const u16* __restrict__ WQf,
    u16* __restrict__ qkvp)
{
  const int l = threadIdx.x & 63, fr = l & 15, fq = l >> 4;
  const int wv = blockIdx.x * 4 + (threadIdx.x >> 6);
  const int nw = gridDim.x * 4;
  short8 A[12][2];
#pragma unroll
  for (int t = 0; t < 12; ++t)
#pragma unroll
    for (int kh = 0; kh < 2; ++kh) A[t][kh] = ldfrag(WQf, t * 2 + kh, l);
  float w0[8], g0[8], w1[8], g1[8];
#pragma unroll
  for (int j = 0; j < 8; ++j) {
    w0[j] = n1w[fq * 8 + j];      g0[j] = n1b[fq * 8 + j];
    w1[j] = n1w[32 + fq * 8 + j]; g1[j] = n1b[32 + fq * 8 + j];
  }
  for (int tile = wv; tile < 8192; tile += nw) {
    const size_t n = (size_t)tile * 16 + fr;
    const int b = (int)(n >> 16);
    const int pix = (int)(n & 65535);
    const float* xb = x + ((size_t)b * 64) * NPB + pix;
    float v0[8], v1[8];
    float s = 0.f;
#pragma unroll
    for (int j = 0; j < 8; ++j) { v0[j] = xb[(size_t)(fq * 8 + j) * NPB]; s += v0[j]; }
#pragma unroll
    for (int j = 0; j < 8; ++j) { v1[j] = xb[(size_t)(32 + fq * 8 + j) * NPB]; s += v1[j]; }
    s += __shfl_xor(s, 16); s += __shfl_xor(s, 32);
    const float mu = s * (1.f / 64.f);
    float ss = 0.f;
#pragma unroll
    for (int j = 0; j < 8; ++j) { float d = v0[j] - mu; ss = fmaf(d, d, ss); }
#pragma unroll
    for (int j = 0; j < 8; ++j) { float d = v1[j] - mu; ss = fmaf(d, d, ss); }
    ss += __shfl_xor(ss, 16); ss += __shfl_xor(ss, 32);
    const float rstd = rsqrtf(ss * (1.f / 64.f) + 1e-5f);
    short8 b0, b1;
#pragma unroll
    for (int j = 0; j < 8; ++j) {
      b0[j] = (short)f2bf((v0[j] - mu) * rstd * w0[j] + g0[j]);
      b1[j] = (short)f2bf((v1[j] - mu) * rstd * w1[j] + g1[j]);
    }
    f32x4 c[12];
#pragma unroll
    for (int t = 0; t < 12; ++t) c[t] = f32x4{0.f, 0.f, 0.f, 0.f};
#pragma unroll
    for (int t = 0; t < 12; ++t) c[t] = mm(A[t][0], b0, c[t]);
#pragma unroll
    for (int t = 0; t < 12; ++t) c[t] = mm(A[t][1], b1, c[t]);
#pragma unroll
    for (int t = 0; t < 12; ++t)
      st4(qkvp + ((size_t)t * NTOT + n) * 16 + fq * 4, c[t]);
  }
}

// ---------------- register-rolling depthwise 3x3 SAME on blocked layout
template<int CH, int STRIP>
__global__ __launch_bounds__(256, 2) void k_dwr(
    const u16* __restrict__ in, u16* __restrict__ out,
    const float* __restrict__ wdw, int wofs)
{
  typedef short __attribute__((ext_vector_type(CH))) shortC;
  constexpr int LPP = 16 / CH;        // lanes per pixel
  constexpr int NX  = 256 / LPP;      // pixels per block in x
  constexpr int XC  = 256 / NX;       // x-chunks per row
  const int t = threadIdx.x;
  const int sub = t % LPP, xi = t / LPP;
  const int q = blockIdx.x / XC, xc = blockIdx.x % XC;
  const int strip = blockIdx.y, b = blockIdx.z;
  const int x = xc * NX + xi;
  const int y0 = strip * STRIP;
  const int e0 = sub * CH;
  const int c0 = q * 16 + e0;

  const u16* pin = in + ((size_t)q * NTOT + (size_t)b * NPB) * 16 + e0;

  float w[9][CH];
#pragma unroll
  for (int ch = 0; ch < CH; ++ch) {
    const int row = wofs + c0 + ch;
#pragma unroll
    for (int tap = 0; tap < 9; ++tap)
      w[tap][ch] = wdw[(size_t)row * 9 + tap];
  }

  auto LD = [&](int yy, int xx) -> shortC {
    shortC v;
#pragma unroll
    for (int j = 0; j < CH; ++j) v[j] = 0;
    if ((unsigned)yy < 256u && (unsigned)xx < 256u)
      v = *reinterpret_cast<const shortC*>(pin + (size_t)(yy * 256 + xx) * 16);
    return v;
  };

  shortC r[3][3];
  r[0][0] = LD(y0 - 1, x - 1); r[0][1] = LD(y0 - 1, x); r[0][2] = LD(y0 - 1, x + 1);
  r[1][0] = LD(y0, x - 1);     r[1][1] = LD(y0, x);     r[1][2] = LD(y0, x + 1);

#pragma unroll 2
  for (int yy = 0; yy < STRIP; ++yy) {
    const int y = y0 + yy;
    r[2][0] = LD(y + 1, x - 1); r[2][1] = LD(y + 1, x); r[2][2] = LD(y + 1, x + 1);
    float acc[CH];
#pragma unroll
    for (int ch = 0; ch < CH; ++ch) acc[ch] = 0.f;
#pragma unroll
    for (int ky = 0; ky < 3; ++ky)
#pragma unroll
      for (int kx = 0; kx < 3; ++kx)
#pragma unroll
        for (int ch = 0; ch < CH; ++ch)
          acc[ch] = fmaf(w[ky * 3 + kx][ch], bf2f((u16)r[ky][kx][ch]), acc[ch]);
    u16* po = out + ((size_t)q * NTOT + (size_t)b * NPB +
                     (size_t)(y * 256 + x)) * 16 + e0;
    uint4 o;
    o.x = pk2(acc[0], acc[1]); o.y = pk2(acc[2], acc[3]);
    o.z = pk2(acc[4], acc[5]); o.w = pk2(acc[6], acc[7]);
    *reinterpret_cast<uint4*>(po) = o;
#pragma unroll
    for (int dx = 0; dx < 3; ++dx) { r[0][dx] = r[1][dx]; r[1][dx] = r[2][dx]; }
  }
}

// ---------------- FUSED: vf = dw3x3(P_b * v); X2 = x + M2_b*vf; Y2 = LN2(X2)
__global__ __launch_bounds__(256, 2) void g_pvdwln(
    const u16* __restrict__ QKV, const u16* __restrict__ Pf,
    const float* __restrict__ wkvd, const u16* __restrict__ M2f,
    const float* __restrict__ x, const float* __restrict__ n2w,
    const float* __restrict__ n2b, u16* __restrict__ X2,
    u16* __restrict__ Y2)
{
  __shared__ __align__(16) u16 sh[336 * 68];        // vfp halo: 64 ch + 4 pad
  __shared__ __align__(16) u16 lds_vf[4 * 256 * 16]; // vf tile, blocked [cb][lpix][16]
  __shared__ __align__(16) u16 swt[9 * 64];          // dw weights bf16 [tap][c]
  const int t = threadIdx.x;
  const int tx0 = blockIdx.x * 16, ty0 = blockIdx.y * 16;
  const int b = blockIdx.z;
  const size_t bofs = (size_t)b * NPB;

  for (int i = t; i < 9 * 64; i += 256) {
    const int tap = i >> 6, c = i & 63;
    swt[i] = f2bf(wkvd[((size_t)(64 + c)) * 9 + tap]);
  }

  const int w = t >> 6, l = t & 63, fr = l & 15, fq = l >> 4;
  short8 A[4][2];
#pragma unroll
  for (int tt = 0; tt < 4; ++tt)
#pragma unroll
    for (int kh = 0; kh < 2; ++kh)
      A[tt][kh] = ldfrag(Pf, (b * 4 + tt) * 2 + kh, l);
  const size_t hof = (size_t)(fq & 1) * 8;

  // --- Phase A: vfp for 21 halo pixel-tiles (rows 0..335, valid 0..323)
  for (int i = w; i < 21; i += 4) {
    const int hidx = i * 16 + fr;
    const int hs = hidx < 323 ? hidx : 323;
    const int py = hs / 18, px = hs % 18;
    const int gy = ty0 + py - 1, gx = tx0 + px - 1;
    const bool ok = ((unsigned)gy < 256u) && ((unsigned)gx < 256u);
    short8 b0, b1;
    if (ok) {
      const size_t pix = bofs + (size_t)(gy * 256 + gx);
      b0 = *reinterpret_cast<const short8*>(
          QKV + ((size_t)(8 + (fq >> 1)) * NTOT + pix) * 16 + hof);
      b1 = *reinterpret_cast<const short8*>(
          QKV + ((size_t)(10 + (fq >> 1)) * NTOT + pix) * 16 + hof);
    } else {
#pragma unroll
      for (int j = 0; j < 8; ++j) { b0[j] = 0; b1[j] = 0; }
    }
    f32x4 c[4];
#pragma unroll
    for (int tt = 0; tt < 4; ++tt) c[tt] = f32x4{0.f, 0.f, 0.f, 0.f};
#pragma unroll
    for (int tt = 0; tt < 4; ++tt) c[tt] = mm(A[tt][0], b0, c[tt]);
#pragma unroll
    for (int tt = 0; tt < 4; ++tt) c[tt] = mm(A[tt][1], b1, c[tt]);
    u16* dp = &sh[hidx * 68];
#pragma unroll
    for (int tt = 0; tt < 4; ++tt) st4(dp + tt * 16 + fq * 4, c[tt]);
  }
  __syncthreads();

  // --- Phase B: dwconv; thread = (4 ch, 1 col, 4 rows); write vf tile to LDS
  {
    const int sub = t & 3, colx = (t >> 2) & 15, rg = t >> 6;
    const int e0 = sub * 4;
    for (int cb = 0; cb < 4; ++cb) {
      float wf[9][4];
#pragma unroll
      for (int tap = 0; tap < 9; ++tap)
#pragma unroll
        for (int j = 0; j < 4; ++j)
          wf[tap][j] = bf2f(swt[tap * 64 + cb * 16 + e0 + j]);
      short4v rwin[3][3];
      auto LDR = [&](int hr, int slot) {
#pragma unroll
        for (int dx = 0; dx < 3; ++dx)
          rwin[slot][dx] = *reinterpret_cast<const short4v*>(
              &sh[(hr * 18 + colx + dx) * 68 + cb * 16 + e0]);
      };
      const int r0 = rg * 4;
      LDR(r0, 0); LDR(r0 + 1, 1);
#pragma unroll
      for (int k = 0; k < 4; ++k) {
        LDR(r0 + k + 2, (k + 2) % 3);
        const int s0 = k % 3, s1 = (k + 1) % 3, s2 = (k + 2) % 3;
        float acc[4] = {0.f, 0.f, 0.f, 0.f};
#pragma unroll
        for (int dx = 0; dx < 3; ++dx)
#pragma unroll
          for (int j = 0; j < 4; ++j) {
            acc[j] = fmaf(wf[0 + dx][j], bf2f((u16)rwin[s0][dx][j]), acc[j]);
            acc[j] = fmaf(wf[3 + dx][j], bf2f((u16)rwin[s1][dx][j]), acc[j]);
            acc[j] = fmaf(wf[6 + dx][j], bf2f((u16)rwin[s2][dx][j]), acc[j]);
          }
        const int lpix = (r0 + k) * 16 + colx;
        uint2 o; o.x = pk2(acc[0], acc[1]); o.y = pk2(acc[2], acc[3]);
        *reinterpret_cast<uint2*>(&lds_vf[(cb * 256 + lpix) * 16 + e0]) = o;
      }
    }
  }
  __syncthreads();

  // --- Phase C: X2 = x + M2_b*vf; Y2 = LN2(X2)  (g_x2ln body, 4 rows/wave)
  {
    short8 Am[4][2];
#pragma unroll
    for (int tt = 0; tt < 4; ++tt)
#pragma unroll
      for (int kh = 0; kh < 2; ++kh)
        Am[tt][kh] = ldfrag(M2f, (b * 4 + tt) * 2 + kh, l);
#pragma unroll
    for (int kk = 0; kk < 4; ++kk) {
      const int row = w * 4 + kk;          // tile row 0..15
      const int lpix = row * 16 + fr;      // pixel within tile
      const int pix = (ty0 + row) * 256 + tx0 + fr;
      const size_t n = bofs + (size_t)pix;
      const short8 b0 = *reinterpret_cast<const short8*>(
          &lds_vf[((size_t)(fq >> 1) * 256 + lpix) * 16 + hof]);
      const short8 b1 = *reinterpret_cast<const short8*>(
          &lds_vf[((size_t)(2 + (fq >> 1)) * 256 + lpix) * 16 + hof]);
      f32x4 c[4];
#pragma unroll
      for (int tt = 0; tt < 4; ++tt) c[tt] = f32x4{0.f, 0.f, 0.f, 0.f};
#pragma unroll
      for (int tt = 0; tt < 4; ++tt) c[tt] = mm(Am[tt][0], b0, c[tt]);
#pragma unroll
      for (int tt = 0; tt < 4; ++tt) c[tt] = mm(Am[tt][1], b1, c[tt]);
#pragma unroll
      for (int tt = 0; tt < 4; ++tt)
#pragma unroll
        for (int r = 0; r < 4; ++r)
          c[tt][r] += x[((size_t)(b * 64 + tt * 16 + fq * 4 + r)) * NPB + pix];
#pragma unroll
      for (int tt = 0; tt < 4; ++tt)
        st4(X2 + ((size_t)tt * NTOT + n) * 16 + fq * 4, c[tt]);
      float s = 0.f;
#pragma unroll
      for (int tt = 0; tt < 4; ++tt)
#pragma unroll
        for (int r = 0; r < 4; ++r) s += c[tt][r];
      s += __shfl_xor(s, 16); s += __shfl_xor(s, 32);
      const float mu = s * (1.f / 64.f);
      float ss = 0.f;
#pragma unroll
      for (int tt = 0; tt < 4; ++tt)
#pragma unroll
        for (int r = 0; r < 4; ++r) { float d = c[tt][r] - mu; ss = fmaf(d, d, ss); }
      ss += __shfl_xor(ss, 16); ss += __shfl_xor(ss, 32);
      const float rstd = rsqrtf(ss * (1.f / 64.f) + 1e-5f);
#pragma unroll
      for (int tt = 0; tt < 4; ++tt)
#pragma unroll
        for (int r = 0; r < 4; ++r) {
          const int oc = tt * 16 + fq * 4 + r;
          c[tt][r] = (c[tt][r] - mu) * rstd * n2w[oc] + n2b[oc];
        }
#pragma unroll
      for (int tt = 0; tt < 4; ++tt)
        st4(Y2 + ((size_t)tt * NTOT + n) * 16 + fq * 4, c[tt]);
    }
  }
}

// ---------------- FUSED: Hg = gelu(dw3x3(Win*Y2)_x1) * dw3x3(Win*Y2)_x2
// 16x16 tile. GEMM phase -> sh (hpre). dwconv phase via MFMA with diagonal-A
// fragments (WDf): 2 taps per mfma (K=32), 5 mfma/plane/row-group; gate is
// elementwise on the two accumulators (D row=channel fq*4+r, col=pixel fr).
__global__ __launch_bounds__(256, 2) void g_windwg(
    const u16* __restrict__ Y2, const u16* __restrict__ WIf,
    const u16* __restrict__ WDf, u16* __restrict__ Hg)
{
  __shared__ __align__(16) u16 sy[336 * 72];    // halo Y2, row stride 72
  __shared__ __align__(16) u16 sh[336 * 36];    // hpre x1(0..15) x2(16..31)
  const int t = threadIdx.x;
  const int tx0 = blockIdx.x * 16, ty0 = blockIdx.y * 16;
  const int b = blockIdx.z;
  const size_t bofs = (size_t)b * NPB;

  for (int idx = t; idx < 336; idx += 256) {
    const int py = idx / 18, px = idx % 18;
    const int gy = ty0 + py - 1, gx = tx0 + px - 1;
    const bool ok = (idx < 324) && ((unsigned)gy < 256u) && ((unsigned)gx < 256u);
#pragma unroll
    for (int cb = 0; cb < 4; ++cb) {
      short8 v0, v1;
      if (ok) {
        const u16* src = Y2 + ((size_t)cb * NTOT + bofs + (size_t)(gy * 256 + gx)) * 16;
        v0 = *reinterpret_cast<const short8*>(src);
        v1 = *reinterpret_cast<const short8*>(src + 8);
      } else {
#pragma unroll
        for (int j = 0; j < 8; ++j) { v0[j] = 0; v1[j] = 0; }
      }
      *reinterpret_cast<short8*>(&sy[idx * 72 + cb * 16]) = v0;
      *reinterpret_cast<short8*>(&sy[idx * 72 + cb * 16 + 8]) = v1;
    }
  }
  __syncthreads();

  const int w = t >> 6, l = t & 63, fr = l & 15, fq = l >> 4;

  for (int q = 0; q < 11; ++q) {
    const short8 a10 = ldfrag(WIf, q * 2, l);
    const short8 a11 = ldfrag(WIf, q * 2 + 1, l);
    const short8 a20 = ldfrag(WIf, (11 + q) * 2, l);
    const short8 a21 = ldfrag(WIf, (11 + q) * 2 + 1, l);
    for (int i = w; i < 21; i += 4) {
      const u16* sp = &sy[(i * 16 + fr) * 72];
      const short8 b0 = *reinterpret_cast<const short8*>(sp + fq * 8);
      const short8 b1 = *reinterpret_cast<const short8*>(sp + 32 + fq * 8);
      f32x4 c1 = {0.f, 0.f, 0.f, 0.f}, c2 = {0.f, 0.f, 0.f, 0.f};
      c1 = mm(a10, b0, c1); c1 = mm(a11, b1, c1);
      c2 = mm(a20, b0, c2); c2 = mm(a21, b1, c2);
      u16* dp = &sh[(i * 16 + fr) * 36];
      st4(dp + fq * 4, c1);
      st4(dp + 16 + fq * 4, c2);
    }
    __syncthreads();

    // --- dwconv+gate via diagonal-A MFMA: per wave 4 output rows g
    short8 AD0[5], AD1[5];
#pragma unroll
    for (int p = 0; p < 5; ++p) {
      AD0[p] = ldfrag(WDf, p * 11 + q, l);
      AD1[p] = ldfrag(WDf, 55 + p * 11 + q, l);
    }
#pragma unroll
    for (int gi = 0; gi < 4; ++gi) {
      const int g = w + gi * 4;
      f32x4 ac1 = {0.f, 0.f, 0.f, 0.f}, ac2 = {0.f, 0.f, 0.f, 0.f};
#pragma unroll
      for (int p = 0; p < 5; ++p) {
        int tap = 2 * p + (fq >> 1);
        if (tap > 8) tap = 8;          // A frag is zero there; B value irrelevant
        const int pos = (g + tap / 3) * 18 + fr + tap % 3;
        const u16* bp = &sh[pos * 36 + (fq & 1) * 8];
        const short4v l0 = *reinterpret_cast<const short4v*>(bp);
        const short4v h0 = *reinterpret_cast<const short4v*>(bp + 4);
        const short4v l1 = *reinterpret_cast<const short4v*>(bp + 16);
        const short4v h1 = *reinterpret_cast<const short4v*>(bp + 20);
        short8 b0v, b1v;
        b0v[0] = l0[0]; b0v[1] = l0[1]; b0v[2] = l0[2]; b0v[3] = l0[3];
        b0v[4] = h0[0]; b0v[5] = h0[1]; b0v[6] = h0[2]; b0v[7] = h0[3];
        b1v[0] = l1[0]; b1v[1] = l1[1]; b1v[2] = l1[2]; b1v[3] = l1[3];
        b1v[4] = h1[0]; b1v[5] = h1[1]; b1v[6] = h1[2]; b1v[7] = h1[3];
        ac1 = mm(AD0[p], b0v, ac1);
        ac2 = mm(AD1[p], b1v, ac2);
      }
      float v[4];
#pragma unroll
      for (int j = 0; j < 4; ++j) v[j] = gelu_t(ac1[j]) * ac2[j];
      const int gy = ty0 + g, gx = tx0 + fr;
      uint2 o; o.x = pk2(v[0], v[1]); o.y = pk2(v[2], v[3]);
      *reinterpret_cast<uint2*>(
          Hg + ((size_t)q * NTOT + bofs + (size_t)(gy * 256 + gx)) * 16 + fq * 4) = o;
    }
    __syncthreads();
  }
}

// ---------------- gram/norm partials via MFMA (blocked: q=block h, k=block 4+h)
__global__ __launch_bounds__(256, 2) void k_gram_p(
    const u16* __restrict__ qkv, float* __restrict__ part)
{
  __shared__ __align__(16) u16 lds[32][520];
  const int chunk = blockIdx.x, h = blockIdx.y, b = blockIdx.z;
  const int t = threadIdx.x;
#pragma unroll
  for (int i = 0; i < 2; ++i) {
    const int p = t + i * 256;
    const size_t pix = (size_t)b * NPB + chunk * 512 + p;
    const u16* srcq = qkv + ((size_t)h * NTOT + pix) * 16;
    const u16* srck = qkv + ((size_t)(4 + h) * NTOT + pix) * 16;
    const short8 q0 = *reinterpret_cast<const short8*>(srcq);
    const short8 q1 = *reinterpret_cast<const short8*>(srcq + 8);
    const short8 k0 = *reinterpret_cast<const short8*>(srck);
    const short8 k1 = *reinterpret_cast<const short8*>(srck + 8);
#pragma unroll
    for (int j = 0; j < 8; ++j) {
      lds[j][p] = (u16)q0[j];  lds[8 + j][p] = (u16)q1[j];
      lds[16 + j][p] = (u16)k0[j]; lds[24 + j][p] = (u16)k1[j];
    }
  }
  __syncthreads();
  const int w = t >> 6, l = t & 63, fr = l & 15, fq = l >> 4;
  if (w >= 3) return;
  float* pp = part + ((size_t)((b * 4 + h) * 128) + chunk) * 288;
  const int rowA = (w == 2) ? 16 + fr : fr;
  const int rowB = (w == 0) ? 16 + fr : rowA;
  f32x4 acc = {0.f, 0.f, 0.f, 0.f};
#pragma unroll
  for (int kt = 0; kt < 16; ++kt) {
    const short8 a  = *reinterpret_cast<const short8*>(&lds[rowA][kt * 32 + fq * 8]);
    const short8 bb = *reinterpret_cast<const short8*>(&lds[rowB][kt * 32 + fq * 8]);
    acc = mm(a, bb, acc);
  }
  if (w == 0) {
#pragma unroll
    for (int r = 0; r < 4; ++r) pp[(fq * 4 + r) * 16 + fr] = acc[r];
  } else if ((fr >> 2) == fq) {
    pp[(w == 1 ? 256 : 272) + fr] = acc[fr & 3];
  }
}

// ---------------- reduce partials over 128 chunks
__global__ __launch_bounds__(320) void k_gram_red(
    const float* __restrict__ part, float* __restrict__ G,
    float* __restrict__ Sq, float* __restrict__ Sk)
{
  const int bh = blockIdx.x;
  const int t = threadIdx.x;
  if (t >= 288) return;
  const float* p = part + (size_t)bh * 128 * 288 + t;
  float s = 0.f;
  for (int ch = 0; ch < 128; ++ch) s += p[(size_t)ch * 288];
  const int b = bh >> 2, h = bh & 3;
  if (t < 256) G[bh * 256 + t] = s;
  else if (t < 272) Sq[b * 64 + h * 16 + (t - 256)] = s;
  else Sk[b * 64 + h * 16 + (t - 272)] = s;
}

// ---------------- softmax + fold conv matrices; emit Pf/M2f fragment layout
__global__ __launch_bounds__(256) void k_attn(
    const float* __restrict__ G, const float* __restrict__ Sq,
    const float* __restrict__ Sk, const float* __restrict__ temp,
    const float* __restrict__ wpo, const float* __restrict__ wkv,
    const float* __restrict__ wpof, u16* __restrict__ Pf,
    u16* __restrict__ M2f)
{
  __shared__ float attn[BATCH][4][16][16];
  __shared__ float M1[BATCH][64][64];
  __shared__ float rq[128], rk[128];
  const int t = threadIdx.x;
  if (t < 128) {
    rq[t] = 1.f / fmaxf(sqrtf(Sq[t]), 1e-12f);
    rk[t] = 1.f / fmaxf(sqrtf(Sk[t]), 1e-12f);
  }
  __syncthreads();
  if (t < 128) {
    const int b = t >> 6, h = (t >> 4) & 3, d = t & 15;
    const float tm = temp[h];
    const float* g = G + ((b * 4 + h) * 16 + d) * 16;
    const float rqd = rq[b * 64 + h * 16 + d];
    float L[16], mx = -1e30f;
#pragma unroll
    for (int e = 0; e < 16; ++e) {
      L[e] = g[e] * rqd * rk[b * 64 + h * 16 + e] * tm;
      mx = fmaxf(mx, L[e]);
    }
    float s = 0.f;
#pragma unroll
    for (int e = 0; e < 16; ++e) { L[e] = expf(L[e] - mx); s += L[e]; }
    const float inv = 1.f / s;
#pragma unroll
    for (int e = 0; e < 16; ++e) attn[b][h][d][e] = L[e] * inv;
  }
  __syncthreads();
  for (int s0 = 0; s0 < 32; ++s0) {
    const int idx = t * 32 + s0;
    const int b = idx >> 12, o = (idx >> 6) & 63, c = idx & 63;
    const int h = c >> 4, e = c & 15;
    float a = 0.f;
#pragma unroll
    for (int d = 0; d < 16; ++d) a = fmaf(wpo[o * 64 + h * 16 + d], attn[b][h][d][e], a);
    M1[b][o][c] = a;
  }
  __syncthreads();
  for (int it = 0; it < 4; ++it) {
    const int idx = it * 256 + t;
    const int l = idx & 63;
    const int fi = idx >> 6;
    const int b = fi >> 3, tt = (fi >> 1) & 3, kh = fi & 1;
    const int fr = l & 15, fq = l >> 4;
    const int o = tt * 16 + fr;
    short8 pv, mv;
#pragma unroll
    for (int j = 0; j < 8; ++j) {
      const int c = kh * 32 + fq * 8 + j;
      const int h = c >> 4, e = c & 15;
      float a2 = 0.f;
#pragma unroll
      for (int d = 0; d < 16; ++d)
        a2 = fmaf(wpof[o * 64 + h * 16 + d], attn[b][h][d][e], a2);
      mv[j] = (short)f2bf(a2);
      float a = 0.f;
      for (int jj = 0; jj < 64; ++jj)
        a = fmaf(wkv[(64 + o) * 64 + jj], M1[b][jj][c], a);
      pv[j] = (short)f2bf(a);
    }
    *reinterpret_cast<short8*>(Pf + ((size_t)fi * 64 + l) * 8) = pv;
    *reinterpret_cast<short8*>(M2f + ((size_t)fi * 64 + l) * 8) = mv;
  }
}

// ---------------- G5: out = X2 + Wout(64x170) * Hg (11 blocks)
__global__ __launch_bounds__(256, 2) void g_out(
    const u16* __restrict__ hg, const u16* __restrict__ WOf,
    const u16* __restrict__ X2, float* __restrict__ out)
{
  const int l = threadIdx.x & 63, fr = l & 15, fq = l >> 4;
  const int wv = blockIdx.x * 4 + (threadIdx.x >> 6);
  const int nw = gridDim.x * 4;
  short8 A[4][6];
#pragma unroll
  for (int t = 0; t < 4; ++t)
#pragma unroll
    for (int kh = 0; kh < 6; ++kh)
      A[t][kh] = ldfrag(WOf, t * 6 + kh, l);
  const size_t hof = (size_t)(fq & 1) * 8;
  for (int tile = wv; tile < 8192; tile += nw) {
    const size_t n = (size_t)tile * 16 + fr;
    short8 bb[6];
#pragma unroll
    for (int kh = 0; kh < 6; ++kh) {
      int hb = kh * 2 + (fq >> 1);
      if (hb > 10) hb = 10;  // k>=170 weights are zero; value irrelevant
      bb[kh] = *reinterpret_cast<const short8*>(
          hg + ((size_t)hb * NTOT + n) * 16 + hof);
    }
    f32x4 c[4];
#pragma unroll
    for (int t = 0; t < 4; ++t) c[t] = f32x4{0.f, 0.f, 0.f, 0.f};
#pragma unroll
    for (int kh = 0; kh < 6; ++kh)
#pragma unroll
      for (int t = 0; t < 4; ++t) c[t] = mm(A[t][kh], bb[kh], c[t]);
    const int b = (int)(n >> 16);
    const int pix = (int)(n & 65535);
#pragma unroll
    for (int t = 0; t < 4; ++t) {
      const uint2 xv = *reinterpret_cast<const uint2*>(
          X2 + ((size_t)t * NTOT + n) * 16 + fq * 4);
      const u16 h0 = (u16)(xv.x & 0xffff), h1 = (u16)(xv.x >> 16);
      const u16 h2 = (u16)(xv.y & 0xffff), h3 = (u16)(xv.y >> 16);
      const int ocb = b * 64 + t * 16 + fq * 4;
      out[((size_t)(ocb + 0)) * NPB + pix] = c[t][0] + bf2f(h0);
      out[((size_t)(ocb + 1)) * NPB + pix] = c[t][1] + bf2f(h1);
      out[((size_t)(ocb + 2)) * NPB + pix] = c[t][2] + bf2f(h2);
      out[((size_t)(ocb + 3)) * NPB + pix] = c[t][3] + bf2f(h3);
    }
  }
}

extern "C" void kernel_launch(void* const* d_in, const int* in_sizes, int n_in,
                              void* d_out, int out_size, void* d_ws, size_t ws_size,
                              hipStream_t stream)
{
  const float* x     = (const float*)d_in[0];
  const float* n1w   = (const float*)d_in[1];
  const float* n1b   = (const float*)d_in[2];
  const float* temp  = (const float*)d_in[3];
  const float* wqkv  = (const float*)d_in[4];
  const float* wqkvd = (const float*)d_in[5];
  const float* wpo   = (const float*)d_in[6];
  const float* wkv   = (const float*)d_in[7];
  const float* wkvd  = (const float*)d_in[8];
  const float* wpof  = (const float*)d_in[9];
  const float* n2w   = (const float*)d_in[10];
  const float* n2b   = (const float*)d_in[11];
  const float* win   = (const float*)d_in[12];
  const float* wdw   = (const float*)d_in[13];
  const float* wout  = (const float*)d_in[14];
  float* out = (float*)d_out;

  char* ws = (char*)d_ws;
  const size_t offA  = 0;                       // 16.78 MB: Y2
  const size_t offB  = 16777216;                // 50.33 MB: QKVp (VF eliminated)
  const size_t offC  = offB + 50331648;         // 50.33 MB: QKV
  const size_t offHg = offC + 50331648;         // 46.14 MB (11 blocks)
  const size_t offX2 = offHg + 46137344 + 256;  // 16.78 MB
  const size_t offSm = offX2 + 16777216;

  u16* Y2   = (u16*)(ws + offA);
  u16* QKVp = (u16*)(ws + offB);
  u16* QKV  = (u16*)(ws + offC);
  u16* Hg   = (u16*)(ws + offHg);
  u16* X2   = (u16*)(ws + offX2);
  float* part = (float*)(ws + offSm);                     // 1,179,648 B
  float* G    = (float*)(ws + offSm + 1179648);           // 8 KB
  float* Sq   = (float*)(ws + offSm + 1179648 + 8192);    // 512 B
  float* Sk   = (float*)(ws + offSm + 1179648 + 8704);    // 512 B
  u16* Pf     = (u16*)(ws + offSm + 1179648 + 9216);      // 16 KB
  u16* M2f    = (u16*)(ws + offSm + 1179648 + 25600);     // 16 KB
  u16* WQf    = (u16*)(ws + offSm + 1179648 + 41984);     // 24 KB
  u16* WIf    = (u16*)(ws + offSm + 1179648 + 66560);     // 44 KB
  u16* WOf    = (u16*)(ws + offSm + 1179648 + 111616);    // 24 KB
  u16* WDf    = (u16*)(ws + offSm + 1179648 + 136192);    // 110 KB (110 frags)

  k_wprep<<<dim3(202), 64, 0, stream>>>(wqkv, win, wout, wdw, WQf, WIf, WOf, WDf);
  // fused LN1 + QKV GEMM (Y1 tensor eliminated)
  g_lnqkv<<<dim3(512), 256, 0, stream>>>(x, n1w, n1b, WQf, QKVp);
  // dw 192ch: 12 blocks x 2 xchunks, 16 strips, 2 batches
  k_dwr<8, 16><<<dim3(24, 16, BATCH), 256, 0, stream>>>(QKVp, QKV, wqkvd, 0);
  k_gram_p<<<dim3(128, 4, BATCH), 256, 0, stream>>>(QKV, part);
  k_gram_red<<<dim3(BATCH * 4), 320, 0, stream>>>(part, G, Sq, Sk);
  k_attn<<<dim3(1), 256, 0, stream>>>(G, Sq, Sk, temp, wpo, wkv, wpof, Pf, M2f);
  // fused PV GEMM + dw 64ch + M2 GEMM + residual + LN2 (VF tensor eliminated)
  g_pvdwln<<<dim3(16, 16, BATCH), 256, 0, stream>>>(
      QKV, Pf, wkvd, M2f, x, n2w, n2b, X2, Y2);
  // fused Win GEMM + MFMA-dwconv gate: 16x16 tiles
  g_windwg<<<dim3(16, 16, BATCH), 256, 0, stream>>>(Y2, WIf, WDf, Hg);
  g_out<<<dim3(512), 256, 0, stream>>>(Hg, WOf, X2, out);
}

// Round 28
// 205.165 us; speedup vs baseline: 1.0711x; 1.0074x over previous
//
#include <hip/hip_runtime.h>
#include <hip/hip_bf16.h>
#include <math.h>

#define NPB 65536   // pixels per batch (256*256)
#define BATCH 2
#define NTOT (BATCH * NPB)   // 131072

typedef unsigned short u16;
typedef __attribute__((ext_vector_type(8))) short short8;
typedef __attribute__((ext_vector_type(4))) short short4v;
typedef __attribute__((ext_vector_type(4))) float f32x4;

// ---- channel-blocked pixel-major layout for all bf16 intermediates:
//   elem(cb, n, c) at  T[((size_t)cb * NTOT + n) * 16 + c],  c in [0,16)
// ---- weight fragments pre-swizzled as [frag][lane(64)][8] bf16.

__device__ __forceinline__ float bf2f(u16 u) {
  union { unsigned u; float f; } v; v.u = ((unsigned)u) << 16; return v.f;
}
__device__ __forceinline__ u16 f2bf(float f) {
  union { float f; unsigned u; } v; v.f = f;
  unsigned r = v.u + 0x7FFFu + ((v.u >> 16) & 1u);
  return (u16)(r >> 16);
}
__device__ __forceinline__ unsigned pk2(float a, float b) {
  return (unsigned)f2bf(a) | ((unsigned)f2bf(b) << 16);
}
__device__ __forceinline__ f32x4 mm(short8 a, short8 b, f32x4 c) {
  return __builtin_amdgcn_mfma_f32_16x16x32_bf16(a, b, c, 0, 0, 0);
}
__device__ __forceinline__ short8 ldfrag(const u16* F, int frag, int l) {
  return *reinterpret_cast<const short8*>(F + ((size_t)frag * 64 + l) * 8);
}
__device__ __forceinline__ void st4(u16* p, f32x4 c) {
  uint2 v; v.x = pk2(c[0], c[1]); v.y = pk2(c[2], c[3]);
  *reinterpret_cast<uint2*>(p) = v;
}
// load a short8 B-frag from an 8B-aligned (not 16B) LDS address
__device__ __forceinline__ short8 ld8u(const u16* bp) {
  const short4v lo = *reinterpret_cast<const short4v*>(bp);
  const short4v hi = *reinterpret_cast<const short4v*>(bp + 4);
  short8 v;
  v[0] = lo[0]; v[1] = lo[1]; v[2] = lo[2]; v[3] = lo[3];
  v[4] = hi[0]; v[5] = hi[1]; v[6] = hi[2]; v[7] = hi[3];
  return v;
}
// tanh-form gelu (max abs err vs exact ~3e-3, validated rounds 9/10/12/13)
__device__ __forceinline__ float gelu_t(float a) {
  const float z = 0.7978845608f * fmaf(0.044715f * a, a * a, a);
  const float e = __expf(2.f * z);
  const float th = 1.f - 2.f / (e + 1.f);
  return 0.5f * a * (1.f + th);
}

// ---------------- W0: pre-swizzle static weights into fragment layout
// f<24: WQf; f<68: WIf; f<92: WOf; f<202: WDf (windwg diag-A dwconv frags);
// f<222: WKf (pvdwln diag-A dwconv frags, wkvd rows 64..127):
//   fd = cb*5 + p; A[ch=fr][k] = wkvd[64+cb*16+fr][tap=2p+(fq>>1)] iff (k&15)==fr.
__global__ __launch_bounds__(64) void k_wprep(
    const float* __restrict__ wqkv, const float* __restrict__ win,
    const float* __restrict__ wout, const float* __restrict__ wdw,
    const float* __restrict__ wkvd,
    u16* __restrict__ WQf, u16* __restrict__ WIf, u16* __restrict__ WOf,
    u16* __restrict__ WDf, u16* __restrict__ WKf)
{
  const int f = blockIdx.x;
  const int l = threadIdx.x;
  const int fr = l & 15, fq = l >> 4;
  short8 v;
  u16* dst;
  if (f < 24) {            // wqkv: frag = t*2+kh, t<12
    const int t = f >> 1, kh = f & 1;
    const int row = t * 16 + fr;
#pragma unroll
    for (int j = 0; j < 8; ++j)
      v[j] = (short)f2bf(wqkv[(size_t)row * 64 + kh * 32 + fq * 8 + j]);
    dst = WQf + ((size_t)f * 64 + l) * 8;
  } else if (f < 68) {     // win: frag = (half*11+t)*2+kh
    const int fi = f - 24;
    const int g = fi >> 1, kh = fi & 1;
    const int half = g / 11, t = g % 11;
    const int col = half * 176 + t * 16 + fr;
    const int row = col < 170 ? col : (col < 176 ? -1 : (col < 346 ? col - 6 : -1));
#pragma unroll
    for (int j = 0; j < 8; ++j)
      v[j] = (row < 0) ? (short)0
             : (short)f2bf(win[(size_t)row * 64 + kh * 32 + fq * 8 + j]);
    dst = WIf + ((size_t)fi * 64 + l) * 8;
  } else if (f < 92) {     // wout: frag = t*6+kh, t<4, kh<6, ld=170
    const int fi = f - 68;
    const int t = fi / 6, kh = fi % 6;
    const int row = t * 16 + fr;
#pragma unroll
    for (int j = 0; j < 8; ++j) {
      const int k = kh * 32 + fq * 8 + j;
      v[j] = (k < 170) ? (short)f2bf(wout[(size_t)row * 170 + k]) : (short)0;
    }
    dst = WOf + ((size_t)fi * 64 + l) * 8;
  } else if (f < 202) {    // WDf: fd = pl*55 + p*11 + q
    const int fd = f - 92;
    const int pl = fd / 55, rest = fd % 55;
    const int p = rest / 11, q = rest % 11;
    const int tap = 2 * p + (fq >> 1);
    const int c = q * 16 + fr;
    const int ts = tap < 9 ? tap : 0;
    const int cs = c < 170 ? c : 0;
    const float wv = wdw[((size_t)(pl * 170 + cs)) * 9 + ts];
    const bool act = (tap < 9) && (c < 170) && ((fq & 1) == (fr >> 3));
#pragma unroll
    for (int j = 0; j < 8; ++j)
      v[j] = (act && j == (fr & 7)) ? (short)f2bf(wv) : (short)0;
    dst = WDf + ((size_t)fd * 64 + l) * 8;
  } else {                 // WKf: fd = cb*5 + p
    const int fd = f - 202;
    const int cb = fd / 5, p = fd % 5;
    const int tap = 2 * p + (fq >> 1);
    const int ts = tap < 9 ? tap : 0;
    const float wv = wkvd[((size_t)(64 + cb * 16 + fr)) * 9 + ts];
    const bool act = (tap < 9) && ((fq & 1) == (fr >> 3));
#pragma unroll
    for (int j = 0; j < 8; ++j)
      v[j] = (act && j == (fr & 7)) ? (short)f2bf(wv) : (short)0;
    dst = WKf + ((size_t)fd * 64 + l) * 8;
  }
  *reinterpret_cast<short8*>(dst) = v;
}

// ---------------- G1 fused: LN1 (over 64 ch) + QKVp (12 blocks) = Wqkv * LN(x)
__global__ __launch_bounds__(256, 2) void g_lnqkv(
    const float* __restrict__ x, const float* __restrict__ n1w,
    const float* __restrict__ n1b, const u16* __restrict__ WQf,
    u16* __restrict__ qkvp)
{
  const int l = threadIdx.x & 63, fr = l & 15, fq = l >> 4;
  const int wv = blockIdx.x * 4 + (threadIdx.x >> 6);
  const int nw = gridDim.x * 4;
  short8 A[12][2];
#pragma unroll
  for (int t = 0; t < 12; ++t)
#pragma unroll
    for (int kh = 0; kh < 2; ++kh) A[t][kh] = ldfrag(WQf, t * 2 + kh, l);
  float w0[8], g0[8], w1[8], g1[8];
#pragma unroll
  for (int j = 0; j < 8; ++j) {
    w0[j] = n1w[fq * 8 + j];      g0[j] = n1b[fq * 8 + j];
    w1[j] = n1w[32 + fq * 8 + j]; g1[j] = n1b[32 + fq * 8 + j];
  }
  for (int tile = wv; tile < 8192; tile += nw) {
    const size_t n = (size_t)tile * 16 + fr;
    const int b = (int)(n >> 16);
    const int pix = (int)(n & 65535);
    const float* xb = x + ((size_t)b * 64) * NPB + pix;
    float v0[8], v1[8];
    float s = 0.f;
#pragma unroll
    for (int j = 0; j < 8; ++j) { v0[j] = xb[(size_t)(fq * 8 + j) * NPB]; s += v0[j]; }
#pragma unroll
    for (int j = 0; j < 8; ++j) { v1[j] = xb[(size_t)(32 + fq * 8 + j) * NPB]; s += v1[j]; }
    s += __shfl_xor(s, 16); s += __shfl_xor(s, 32);
    const float mu = s * (1.f / 64.f);
    float ss = 0.f;
#pragma unroll
    for (int j = 0; j < 8; ++j) { float d = v0[j] - mu; ss = fmaf(d, d, ss); }
#pragma unroll
    for (int j = 0; j < 8; ++j) { float d = v1[j] - mu; ss = fmaf(d, d, ss); }
    ss += __shfl_xor(ss, 16); ss += __shfl_xor(ss, 32);
    const float rstd = rsqrtf(ss * (1.f / 64.f) + 1e-5f);
    short8 b0, b1;
#pragma unroll
    for (int j = 0; j < 8; ++j) {
      b0[j] = (short)f2bf((v0[j] - mu) * rstd * w0[j] + g0[j]);
      b1[j] = (short)f2bf((v1[j] - mu) * rstd * w1[j] + g1[j]);
    }
    f32x4 c[12];
#pragma unroll
    for (int t = 0; t < 12; ++t) c[t] = f32x4{0.f, 0.f, 0.f, 0.f};
#pragma unroll
    for (int t = 0; t < 12; ++t) c[t] = mm(A[t][0], b0, c[t]);
#pragma unroll
    for (int t = 0; t < 12; ++t) c[t] = mm(A[t][1], b1, c[t]);
#pragma unroll
    for (int t = 0; t < 12; ++t)
      st4(qkvp + ((size_t)t * NTOT + n) * 16 + fq * 4, c[t]);
  }
}

// ---------------- register-rolling depthwise 3x3 SAME on blocked layout
template<int CH, int STRIP>
__global__ __launch_bounds__(256, 2) void k_dwr(
    const u16* __restrict__ in, u16* __restrict__ out,
    const float* __restrict__ wdw, int wofs)
{
  typedef short __attribute__((ext_vector_type(CH))) shortC;
  constexpr int LPP = 16 / CH;        // lanes per pixel
  constexpr int NX  = 256 / LPP;      // pixels per block in x
  constexpr int XC  = 256 / NX;       // x-chunks per row
  const int t = threadIdx.x;
  const int sub = t % LPP, xi = t / LPP;
  const int q = blockIdx.x / XC, xc = blockIdx.x % XC;
  const int strip = blockIdx.y, b = blockIdx.z;
  const int x = xc * NX + xi;
  const int y0 = strip * STRIP;
  const int e0 = sub * CH;
  const int c0 = q * 16 + e0;

  const u16* pin = in + ((size_t)q * NTOT + (size_t)b * NPB) * 16 + e0;

  float w[9][CH];
#pragma unroll
  for (int ch = 0; ch < CH; ++ch) {
    const int row = wofs + c0 + ch;
#pragma unroll
    for (int tap = 0; tap < 9; ++tap)
      w[tap][ch] = wdw[(size_t)row * 9 + tap];
  }

  auto LD = [&](int yy, int xx) -> shortC {
    shortC v;
#pragma unroll
    for (int j = 0; j < CH; ++j) v[j] = 0;
    if ((unsigned)yy < 256u && (unsigned)xx < 256u)
      v = *reinterpret_cast<const shortC*>(pin + (size_t)(yy * 256 + xx) * 16);
    return v;
  };

  shortC r[3][3];
  r[0][0] = LD(y0 - 1, x - 1); r[0][1] = LD(y0 - 1, x); r[0][2] = LD(y0 - 1, x + 1);
  r[1][0] = LD(y0, x - 1);     r[1][1] = LD(y0, x);     r[1][2] = LD(y0, x + 1);

#pragma unroll 2
  for (int yy = 0; yy < STRIP; ++yy) {
    const int y = y0 + yy;
    r[2][0] = LD(y + 1, x - 1); r[2][1] = LD(y + 1, x); r[2][2] = LD(y + 1, x + 1);
    float acc[CH];
#pragma unroll
    for (int ch = 0; ch < CH; ++ch) acc[ch] = 0.f;
#pragma unroll
    for (int ky = 0; ky < 3; ++ky)
#pragma unroll
      for (int kx = 0; kx < 3; ++kx)
#pragma unroll
        for (int ch = 0; ch < CH; ++ch)
          acc[ch] = fmaf(w[ky * 3 + kx][ch], bf2f((u16)r[ky][kx][ch]), acc[ch]);
    u16* po = out + ((size_t)q * NTOT + (size_t)b * NPB +
                     (size_t)(y * 256 + x)) * 16 + e0;
    uint4 o;
    o.x = pk2(acc[0], acc[1]); o.y = pk2(acc[2], acc[3]);
    o.z = pk2(acc[4], acc[5]); o.w = pk2(acc[6], acc[7]);
    *reinterpret_cast<uint4*>(po) = o;
#pragma unroll
    for (int dx = 0; dx < 3; ++dx) { r[0][dx] = r[1][dx]; r[1][dx] = r[2][dx]; }
  }
}

// ---------------- FUSED: vf = dw3x3(P_b * v); X2 = x + M2_b*vf; Y2 = LN2(X2)
// Phase A: PV GEMM -> sh halo. Phase B: dwconv via diagonal-A MFMA (WKf) ->
// lds_vf. Phase C: M2 GEMM + residual + LN2 -> X2, Y2.
__global__ __launch_bounds__(256, 2) void g_pvdwln(
    const u16* __restrict__ QKV, const u16* __restrict__ Pf,
    const u16* __restrict__ WKf, const u16* __restrict__ M2f,
    const float* __restrict__ x, const float* __restrict__ n2w,
    const float* __restrict__ n2b, u16* __restrict__ X2,
    u16* __restrict__ Y2)
{
  __shared__ __align__(16) u16 sh[336 * 68];        // vfp halo: 64 ch + 4 pad
  __shared__ __align__(16) u16 lds_vf[4 * 256 * 16]; // vf tile, blocked [cb][lpix][16]
  const int t = threadIdx.x;
  const int tx0 = blockIdx.x * 16, ty0 = blockIdx.y * 16;
  const int b = blockIdx.z;
  const size_t bofs = (size_t)b * NPB;

  const int w = t >> 6, l = t & 63, fr = l & 15, fq = l >> 4;
  short8 A[4][2];
#pragma unroll
  for (int tt = 0; tt < 4; ++tt)
#pragma unroll
    for (int kh = 0; kh < 2; ++kh)
      A[tt][kh] = ldfrag(Pf, (b * 4 + tt) * 2 + kh, l);
  const size_t hof = (size_t)(fq & 1) * 8;

  // --- Phase A: vfp for 21 halo pixel-tiles (rows 0..335, valid 0..323)
  for (int i = w; i < 21; i += 4) {
    const int hidx = i * 16 + fr;
    const int hs = hidx < 323 ? hidx : 323;
    const int py = hs / 18, px = hs % 18;
    const int gy = ty0 + py - 1, gx = tx0 + px - 1;
    const bool ok = ((unsigned)gy < 256u) && ((unsigned)gx < 256u);
    short8 b0, b1;
    if (ok) {
      const size_t pix = bofs + (size_t)(gy * 256 + gx);
      b0 = *reinterpret_cast<const short8*>(
          QKV + ((size_t)(8 + (fq >> 1)) * NTOT + pix) * 16 + hof);
      b1 = *reinterpret_cast<const short8*>(
          QKV + ((size_t)(10 + (fq >> 1)) * NTOT + pix) * 16 + hof);
    } else {
#pragma unroll
      for (int j = 0; j < 8; ++j) { b0[j] = 0; b1[j] = 0; }
    }
    f32x4 c[4];
#pragma unroll
    for (int tt = 0; tt < 4; ++tt) c[tt] = f32x4{0.f, 0.f, 0.f, 0.f};
#pragma unroll
    for (int tt = 0; tt < 4; ++tt) c[tt] = mm(A[tt][0], b0, c[tt]);
#pragma unroll
    for (int tt = 0; tt < 4; ++tt) c[tt] = mm(A[tt][1], b1, c[tt]);
    u16* dp = &sh[hidx * 68];
#pragma unroll
    for (int tt = 0; tt < 4; ++tt) st4(dp + tt * 16 + fq * 4, c[tt]);
  }
  __syncthreads();

  // --- Phase B: dwconv via diagonal-A MFMA; wave covers rows w, w+4, w+8, w+12
  for (int cb = 0; cb < 4; ++cb) {
    short8 AK[5];
#pragma unroll
    for (int p = 0; p < 5; ++p) AK[p] = ldfrag(WKf, cb * 5 + p, l);
#pragma unroll
    for (int gi = 0; gi < 4; ++gi) {
      const int g = w + gi * 4;
      f32x4 ac = {0.f, 0.f, 0.f, 0.f};
#pragma unroll
      for (int p = 0; p < 5; ++p) {
        int tap = 2 * p + (fq >> 1);
        if (tap > 8) tap = 8;          // A frag is zero there; B value irrelevant
        const int pos = (g + tap / 3) * 18 + fr + tap % 3;
        ac = mm(AK[p], ld8u(&sh[pos * 68 + cb * 16 + (fq & 1) * 8]), ac);
      }
      const int lpix = g * 16 + fr;
      st4(&lds_vf[(cb * 256 + lpix) * 16 + fq * 4], ac);
    }
  }
  __syncthreads();

  // --- Phase C: X2 = x + M2_b*vf; Y2 = LN2(X2)  (g_x2ln body, 4 rows/wave)
  {
    short8 Am[4][2];
#pragma unroll
    for (int tt = 0; tt < 4; ++tt)
#pragma unroll
      for (int kh = 0; kh < 2; ++kh)
        Am[tt][kh] = ldfrag(M2f, (b * 4 + tt) * 2 + kh, l);
#pragma unroll
    for (int kk = 0; kk < 4; ++kk) {
      const int row = w * 4 + kk;          // tile row 0..15
      const int lpix = row * 16 + fr;      // pixel within tile
      const int pix = (ty0 + row) * 256 + tx0 + fr;
      const size_t n = bofs + (size_t)pix;
      const short8 b0 = *reinterpret_cast<const short8*>(
          &lds_vf[((size_t)(fq >> 1) * 256 + lpix) * 16 + hof]);
      const short8 b1 = *reinterpret_cast<const short8*>(
          &lds_vf[((size_t)(2 + (fq >> 1)) * 256 + lpix) * 16 + hof]);
      f32x4 c[4];
#pragma unroll
      for (int tt = 0; tt < 4; ++tt) c[tt] = f32x4{0.f, 0.f, 0.f, 0.f};
#pragma unroll
      for (int tt = 0; tt < 4; ++tt) c[tt] = mm(Am[tt][0], b0, c[tt]);
#pragma unroll
      for (int tt = 0; tt < 4; ++tt) c[tt] = mm(Am[tt][1], b1, c[tt]);
#pragma unroll
      for (int tt = 0; tt < 4; ++tt)
#pragma unroll
        for (int r = 0; r < 4; ++r)
          c[tt][r] += x[((size_t)(b * 64 + tt * 16 + fq * 4 + r)) * NPB + pix];
#pragma unroll
      for (int tt = 0; tt < 4; ++tt)
        st4(X2 + ((size_t)tt * NTOT + n) * 16 + fq * 4, c[tt]);
      float s = 0.f;
#pragma unroll
      for (int tt = 0; tt < 4; ++tt)
#pragma unroll
        for (int r = 0; r < 4; ++r) s += c[tt][r];
      s += __shfl_xor(s, 16); s += __shfl_xor(s, 32);
      const float mu = s * (1.f / 64.f);
      float ss = 0.f;
#pragma unroll
      for (int tt = 0; tt < 4; ++tt)
#pragma unroll
        for (int r = 0; r < 4; ++r) { float d = c[tt][r] - mu; ss = fmaf(d, d, ss); }
      ss += __shfl_xor(ss, 16); ss += __shfl_xor(ss, 32);
      const float rstd = rsqrtf(ss * (1.f / 64.f) + 1e-5f);
#pragma unroll
      for (int tt = 0; tt < 4; ++tt)
#pragma unroll
        for (int r = 0; r < 4; ++r) {
          const int oc = tt * 16 + fq * 4 + r;
          c[tt][r] = (c[tt][r] - mu) * rstd * n2w[oc] + n2b[oc];
        }
#pragma unroll
      for (int tt = 0; tt < 4; ++tt)
        st4(Y2 + ((size_t)tt * NTOT + n) * 16 + fq * 4, c[tt]);
    }
  }
}

// ---------------- FUSED: Hg = gelu(dw3x3(Win*Y2)_x1) * dw3x3(Win*Y2)_x2
// 16x16 tile. GEMM phase -> sh (hpre). dwconv phase via MFMA with diagonal-A
// fragments (WDf): 2 taps per mfma (K=32), 5 mfma/plane/row-group; gate is
// elementwise on the two accumulators (D row=channel fq*4+r, col=pixel fr).
__global__ __launch_bounds__(256, 2) void g_windwg(
    const u16* __restrict__ Y2, const u16* __restrict__ WIf,
    const u16* __restrict__ WDf, u16* __restrict__ Hg)
{
  __shared__ __align__(16) u16 sy[336 * 72];    // halo Y2, row stride 72
  __shared__ __align__(16) u16 sh[336 * 36];    // hpre x1(0..15) x2(16..31)
  const int t = threadIdx.x;
  const int tx0 = blockIdx.x * 16, ty0 = blockIdx.y * 16;
  const int b = blockIdx.z;
  const size_t bofs = (size_t)b * NPB;

  for (int idx = t; idx < 336; idx += 256) {
    const int py = idx / 18, px = idx % 18;
    const int gy = ty0 + py - 1, gx = tx0 + px - 1;
    const bool ok = (idx < 324) && ((unsigned)gy < 256u) && ((unsigned)gx < 256u);
#pragma unroll
    for (int cb = 0; cb < 4; ++cb) {
      short8 v0, v1;
      if (ok) {
        const u16* src = Y2 + ((size_t)cb * NTOT + bofs + (size_t)(gy * 256 + gx)) * 16;
        v0 = *reinterpret_cast<const short8*>(src);
        v1 = *reinterpret_cast<const short8*>(src + 8);
      } else {
#pragma unroll
        for (int j = 0; j < 8; ++j) { v0[j] = 0; v1[j] = 0; }
      }
      *reinterpret_cast<short8*>(&sy[idx * 72 + cb * 16]) = v0;
      *reinterpret_cast<short8*>(&sy[idx * 72 + cb * 16 + 8]) = v1;
    }
  }
  __syncthreads();

  const int w = t >> 6, l = t & 63, fr = l & 15, fq = l >> 4;

  for (int q = 0; q < 11; ++q) {
    const short8 a10 = ldfrag(WIf, q * 2, l);
    const short8 a11 = ldfrag(WIf, q * 2 + 1, l);
    const short8 a20 = ldfrag(WIf, (11 + q) * 2, l);
    const short8 a21 = ldfrag(WIf, (11 + q) * 2 + 1, l);
    for (int i = w; i < 21; i += 4) {
      const u16* sp = &sy[(i * 16 + fr) * 72];
      const short8 b0 = *reinterpret_cast<const short8*>(sp + fq * 8);
      const short8 b1 = *reinterpret_cast<const short8*>(sp + 32 + fq * 8);
      f32x4 c1 = {0.f, 0.f, 0.f, 0.f}, c2 = {0.f, 0.f, 0.f, 0.f};
      c1 = mm(a10, b0, c1); c1 = mm(a11, b1, c1);
      c2 = mm(a20, b0, c2); c2 = mm(a21, b1, c2);
      u16* dp = &sh[(i * 16 + fr) * 36];
      st4(dp + fq * 4, c1);
      st4(dp + 16 + fq * 4, c2);
    }
    __syncthreads();

    // --- dwconv+gate via diagonal-A MFMA: per wave 4 output rows g
    short8 AD0[5], AD1[5];
#pragma unroll
    for (int p = 0; p < 5; ++p) {
      AD0[p] = ldfrag(WDf, p * 11 + q, l);
      AD1[p] = ldfrag(WDf, 55 + p * 11 + q, l);
    }
#pragma unroll
    for (int gi = 0; gi < 4; ++gi) {
      const int g = w + gi * 4;
      f32x4 ac1 = {0.f, 0.f, 0.f, 0.f}, ac2 = {0.f, 0.f, 0.f, 0.f};
#pragma unroll
      for (int p = 0; p < 5; ++p) {
        int tap = 2 * p + (fq >> 1);
        if (tap > 8) tap = 8;          // A frag is zero there; B value irrelevant
        const int pos = (g + tap / 3) * 18 + fr + tap % 3;
        const u16* bp = &sh[pos * 36 + (fq & 1) * 8];
        ac1 = mm(AD0[p], ld8u(bp), ac1);
        ac2 = mm(AD1[p], ld8u(bp + 16), ac2);
      }
      float v[4];
#pragma unroll
      for (int j = 0; j < 4; ++j) v[j] = gelu_t(ac1[j]) * ac2[j];
      const int gy = ty0 + g, gx = tx0 + fr;
      uint2 o; o.x = pk2(v[0], v[1]); o.y = pk2(v[2], v[3]);
      *reinterpret_cast<uint2*>(
          Hg + ((size_t)q * NTOT + bofs + (size_t)(gy * 256 + gx)) * 16 + fq * 4) = o;
    }
    __syncthreads();
  }
}

// ---------------- gram/norm partials via MFMA (blocked: q=block h, k=block 4+h)
__global__ __launch_bounds__(256, 2) void k_gram_p(
    const u16* __restrict__ qkv, float* __restrict__ part)
{
  __shared__ __align__(16) u16 lds[32][520];
  const int chunk = blockIdx.x, h = blockIdx.y, b = blockIdx.z;
  const int t = threadIdx.x;
#pragma unroll
  for (int i = 0; i < 2; ++i) {
    const int p = t + i * 256;
    const size_t pix = (size_t)b * NPB + chunk * 512 + p;
    const u16* srcq = qkv + ((size_t)h * NTOT + pix) * 16;
    const u16* srck = qkv + ((size_t)(4 + h) * NTOT + pix) * 16;
    const short8 q0 = *reinterpret_cast<const short8*>(srcq);
    const short8 q1 = *reinterpret_cast<const short8*>(srcq + 8);
    const short8 k0 = *reinterpret_cast<const short8*>(srck);
    const short8 k1 = *reinterpret_cast<const short8*>(srck + 8);
#pragma unroll
    for (int j = 0; j < 8; ++j) {
      lds[j][p] = (u16)q0[j];  lds[8 + j][p] = (u16)q1[j];
      lds[16 + j][p] = (u16)k0[j]; lds[24 + j][p] = (u16)k1[j];
    }
  }
  __syncthreads();
  const int w = t >> 6, l = t & 63, fr = l & 15, fq = l >> 4;
  if (w >= 3) return;
  float* pp = part + ((size_t)((b * 4 + h) * 128) + chunk) * 288;
  const int rowA = (w == 2) ? 16 + fr : fr;
  const int rowB = (w == 0) ? 16 + fr : rowA;
  f32x4 acc = {0.f, 0.f, 0.f, 0.f};
#pragma unroll
  for (int kt = 0; kt < 16; ++kt) {
    const short8 a  = *reinterpret_cast<const short8*>(&lds[rowA][kt * 32 + fq * 8]);
    const short8 bb = *reinterpret_cast<const short8*>(&lds[rowB][kt * 32 + fq * 8]);
    acc = mm(a, bb, acc);
  }
  if (w == 0) {
#pragma unroll
    for (int r = 0; r < 4; ++r) pp[(fq * 4 + r) * 16 + fr] = acc[r];
  } else if ((fr >> 2) == fq) {
    pp[(w == 1 ? 256 : 272) + fr] = acc[fr & 3];
  }
}

// ---------------- reduce partials over 128 chunks
__global__ __launch_bounds__(320) void k_gram_red(
    const float* __restrict__ part, float* __restrict__ G,
    float* __restrict__ Sq, float* __restrict__ Sk)
{
  const int bh = blockIdx.x;
  const int t = threadIdx.x;
  if (t >= 288) return;
  const float* p = part + (size_t)bh * 128 * 288 + t;
  float s = 0.f;
  for (int ch = 0; ch < 128; ++ch) s += p[(size_t)ch * 288];
  const int b = bh >> 2, h = bh & 3;
  if (t < 256) G[bh * 256 + t] = s;
  else if (t < 272) Sq[b * 64 + h * 16 + (t - 256)] = s;
  else Sk[b * 64 + h * 16 + (t - 272)] = s;
}

// ---------------- softmax + fold conv matrices; emit Pf/M2f fragment layout
__global__ __launch_bounds__(256) void k_attn(
    const float* __restrict__ G, const float* __restrict__ Sq,
    const float* __restrict__ Sk, const float* __restrict__ temp,
    const float* __restrict__ wpo, const float* __restrict__ wkv,
    const float* __restrict__ wpof, u16* __restrict__ Pf,
    u16* __restrict__ M2f)
{
  __shared__ float attn[BATCH][4][16][16];
  __shared__ float M1[BATCH][64][64];
  __shared__ float rq[128], rk[128];
  const int t = threadIdx.x;
  if (t < 128) {
    rq[t] = 1.f / fmaxf(sqrtf(Sq[t]), 1e-12f);
    rk[t] = 1.f / fmaxf(sqrtf(Sk[t]), 1e-12f);
  }
  __syncthreads();
  if (t < 128) {
    const int b = t >> 6, h = (t >> 4) & 3, d = t & 15;
    const float tm = temp[h];
    const float* g = G + ((b * 4 + h) * 16 + d) * 16;
    const float rqd = rq[b * 64 + h * 16 + d];
    float L[16], mx = -1e30f;
#pragma unroll
    for (int e = 0; e < 16; ++e) {
      L[e] = g[e] * rqd * rk[b * 64 + h * 16 + e] * tm;
      mx = fmaxf(mx, L[e]);
    }
    float s = 0.f;
#pragma unroll
    for (int e = 0; e < 16; ++e) { L[e] = expf(L[e] - mx); s += L[e]; }
    const float inv = 1.f / s;
#pragma unroll
    for (int e = 0; e < 16; ++e) attn[b][h][d][e] = L[e] * inv;
  }
  __syncthreads();
  for (int s0 = 0; s0 < 32; ++s0) {
    const int idx = t * 32 + s0;
    const int b = idx >> 12, o = (idx >> 6) & 63, c = idx & 63;
    const int h = c >> 4, e = c & 15;
    float a = 0.f;
#pragma unroll
    for (int d = 0; d < 16; ++d) a = fmaf(wpo[o * 64 + h * 16 + d], attn[b][h][d][e], a);
    M1[b][o][c] = a;
  }
  __syncthreads();
  for (int it = 0; it < 4; ++it) {
    const int idx = it * 256 + t;
    const int l = idx & 63;
    const int fi = idx >> 6;
    const int b = fi >> 3, tt = (fi >> 1) & 3, kh = fi & 1;
    const int fr = l & 15, fq = l >> 4;
    const int o = tt * 16 + fr;
    short8 pv, mv;
#pragma unroll
    for (int j = 0; j < 8; ++j) {
      const int c = kh * 32 + fq * 8 + j;
      const int h = c >> 4, e = c & 15;
      float a2 = 0.f;
#pragma unroll
      for (int d = 0; d < 16; ++d)
        a2 = fmaf(wpof[o * 64 + h * 16 + d], attn[b][h][d][e], a2);
      mv[j] = (short)f2bf(a2);
      float a = 0.f;
      for (int jj = 0; jj < 64; ++jj)
        a = fmaf(wkv[(64 + o) * 64 + jj], M1[b][jj][c], a);
      pv[j] = (short)f2bf(a);
    }
    *reinterpret_cast<short8*>(Pf + ((size_t)fi * 64 + l) * 8) = pv;
    *reinterpret_cast<short8*>(M2f + ((size_t)fi * 64 + l) * 8) = mv;
  }
}

// ---------------- G5: out = X2 + Wout(64x170) * Hg (11 blocks)
__global__ __launch_bounds__(256, 2) void g_out(
    const u16* __restrict__ hg, const u16* __restrict__ WOf,
    const u16* __restrict__ X2, float* __restrict__ out)
{
  const int l = threadIdx.x & 63, fr = l & 15, fq = l >> 4;
  const int wv = blockIdx.x * 4 + (threadIdx.x >> 6);
  const int nw = gridDim.x * 4;
  short8 A[4][6];
#pragma unroll
  for (int t = 0; t < 4; ++t)
#pragma unroll
    for (int kh = 0; kh < 6; ++kh)
      A[t][kh] = ldfrag(WOf, t * 6 + kh, l);
  const size_t hof = (size_t)(fq & 1) * 8;
  for (int tile = wv; tile < 8192; tile += nw) {
    const size_t n = (size_t)tile * 16 + fr;
    short8 bb[6];
#pragma unroll
    for (int kh = 0; kh < 6; ++kh) {
      int hb = kh * 2 + (fq >> 1);
      if (hb > 10) hb = 10;  // k>=170 weights are zero; value irrelevant
      bb[kh] = *reinterpret_cast<const short8*>(
          hg + ((size_t)hb * NTOT + n) * 16 + hof);
    }
    f32x4 c[4];
#pragma unroll
    for (int t = 0; t < 4; ++t) c[t] = f32x4{0.f, 0.f, 0.f, 0.f};
#pragma unroll
    for (int kh = 0; kh < 6; ++kh)
#pragma unroll
      for (int t = 0; t < 4; ++t) c[t] = mm(A[t][kh], bb[kh], c[t]);
    const int b = (int)(n >> 16);
    const int pix = (int)(n & 65535);
#pragma unroll
    for (int t = 0; t < 4; ++t) {
      const uint2 xv = *reinterpret_cast<const uint2*>(
          X2 + ((size_t)t * NTOT + n) * 16 + fq * 4);
      const u16 h0 = (u16)(xv.x & 0xffff), h1 = (u16)(xv.x >> 16);
      const u16 h2 = (u16)(xv.y & 0xffff), h3 = (u16)(xv.y >> 16);
      const int ocb = b * 64 + t * 16 + fq * 4;
      out[((size_t)(ocb + 0)) * NPB + pix] = c[t][0] + bf2f(h0);
      out[((size_t)(ocb + 1)) * NPB + pix] = c[t][1] + bf2f(h1);
      out[((size_t)(ocb + 2)) * NPB + pix] = c[t][2] + bf2f(h2);
      out[((size_t)(ocb + 3)) * NPB + pix] = c[t][3] + bf2f(h3);
    }
  }
}

extern "C" void kernel_launch(void* const* d_in, const int* in_sizes, int n_in,
                              void* d_out, int out_size, void* d_ws, size_t ws_size,
                              hipStream_t stream)
{
  const float* x     = (const float*)d_in[0];
  const float* n1w   = (const float*)d_in[1];
  const float* n1b   = (const float*)d_in[2];
  const float* temp  = (const float*)d_in[3];
  const float* wqkv  = (const float*)d_in[4];
  const float* wqkvd = (const float*)d_in[5];
  const float* wpo   = (const float*)d_in[6];
  const float* wkv   = (const float*)d_in[7];
  const float* wkvd  = (const float*)d_in[8];
  const float* wpof  = (const float*)d_in[9];
  const float* n2w   = (const float*)d_in[10];
  const float* n2b   = (const float*)d_in[11];
  const float* win   = (const float*)d_in[12];
  const float* wdw   = (const float*)d_in[13];
  const float* wout  = (const float*)d_in[14];
  float* out = (float*)d_out;

  char* ws = (char*)d_ws;
  const size_t offA  = 0;                       // 16.78 MB: Y2
  const size_t offB  = 16777216;                // 50.33 MB: QKVp (VF eliminated)
  const size_t offC  = offB + 50331648;         // 50.33 MB: QKV
  const size_t offHg = offC + 50331648;         // 46.14 MB (11 blocks)
  const size_t offX2 = offHg + 46137344 + 256;  // 16.78 MB
  const size_t offSm = offX2 + 16777216;

  u16* Y2   = (u16*)(ws + offA);
  u16* QKVp = (u16*)(ws + offB);
  u16* QKV  = (u16*)(ws + offC);
  u16* Hg   = (u16*)(ws + offHg);
  u16* X2   = (u16*)(ws + offX2);
  float* part = (float*)(ws + offSm);                     // 1,179,648 B
  float* G    = (float*)(ws + offSm + 1179648);           // 8 KB
  float* Sq   = (float*)(ws + offSm + 1179648 + 8192);    // 512 B
  float* Sk   = (float*)(ws + offSm + 1179648 + 8704);    // 512 B
  u16* Pf     = (u16*)(ws + offSm + 1179648 + 9216);      // 16 KB
  u16* M2f    = (u16*)(ws + offSm + 1179648 + 25600);     // 16 KB
  u16* WQf    = (u16*)(ws + offSm + 1179648 + 41984);     // 24 KB
  u16* WIf    = (u16*)(ws + offSm + 1179648 + 66560);     // 44 KB
  u16* WOf    = (u16*)(ws + offSm + 1179648 + 111616);    // 24 KB
  u16* WDf    = (u16*)(ws + offSm + 1179648 + 136192);    // 110 KB (110 frags)
  u16* WKf    = (u16*)(ws + offSm + 1179648 + 248832);    // 20 KB (20 frags)

  k_wprep<<<dim3(222), 64, 0, stream>>>(wqkv, win, wout, wdw, wkvd,
                                        WQf, WIf, WOf, WDf, WKf);
  // fused LN1 + QKV GEMM (Y1 tensor eliminated)
  g_lnqkv<<<dim3(512), 256, 0, stream>>>(x, n1w, n1b, WQf, QKVp);
  // dw 192ch: 12 blocks x 2 xchunks, 16 strips, 2 batches
  k_dwr<8, 16><<<dim3(24, 16, BATCH), 256, 0, stream>>>(QKVp, QKV, wqkvd, 0);
  k_gram_p<<<dim3(128, 4, BATCH), 256, 0, stream>>>(QKV, part);
  k_gram_red<<<dim3(BATCH * 4), 320, 0, stream>>>(part, G, Sq, Sk);
  k_attn<<<dim3(1), 256, 0, stream>>>(G, Sq, Sk, temp, wpo, wkv, wpof, Pf, M2f);
  // fused PV GEMM + MFMA-dwconv + M2 GEMM + residual + LN2
  g_pvdwln<<<dim3(16, 16, BATCH), 256, 0, stream>>>(
      QKV, Pf, WKf, M2f, x, n2w, n2b, X2, Y2);
  // fused Win GEMM + MFMA-dwconv gate: 16x16 tiles
  g_windwg<<<dim3(16, 16, BATCH), 256, 0, stream>>>(Y2, WIf, WDf, Hg);
  g_out<<<dim3(512), 256, 0, stream>>>(Hg, WOf, X2, out);
}